// Round 10
// baseline (501.654 us; speedup 1.0000x reference)
//
#include <hip/hip_runtime.h>
#include <hip/hip_bf16.h>

#define NN 50000
#define TT 16
#define DD 4
#define EE 800000
#define HH 4
#define HID 32
#define THID 64
#define HD 16

typedef __attribute__((ext_vector_type(8))) short bf16x8;
typedef __attribute__((ext_vector_type(4))) float f32x4;
typedef __attribute__((ext_vector_type(2))) float f32x2;
typedef __attribute__((ext_vector_type(4))) unsigned u32x4;
typedef __attribute__((ext_vector_type(4))) _Float16 h4;

__device__ __forceinline__ unsigned short f2bf(float f){
    unsigned u = __float_as_uint(f);
    u = u + 0x7fffu + ((u >> 16) & 1u);   // RNE
    return (unsigned short)(u >> 16);
}
__device__ __forceinline__ unsigned pk2(float a, float b){
    return (unsigned)f2bf(a) | ((unsigned)f2bf(b) << 16);
}
// HW packed f32->bf16 (T12 recipe; no builtin on gfx950). Replaces ~6-op bit-math.
__device__ __forceinline__ unsigned cvtpk(float a, float b){
    unsigned r;
    asm("v_cvt_pk_bf16_f32 %0, %1, %2" : "=v"(r) : "v"(a), "v"(b));
    return r;
}
__device__ __forceinline__ bf16x8 mk8(unsigned a0, unsigned a1, unsigned a2, unsigned a3){
    u32x4 u = {a0, a1, a2, a3};
    return __builtin_bit_cast(bf16x8, u);
}
// Build an 8-bf16 operand fragment from a C-fragment's packed dword pair via 4 shfls.
__device__ __forceinline__ bf16x8 gather8(int d0, int d1, int s0, int s1, bool zero){
    int a0 = __shfl(d0, s0, 64);
    int a1 = __shfl(d1, s0, 64);
    int a2 = __shfl(d0, s1, 64);
    int a3 = __shfl(d1, s1, 64);
    if (zero){ a0 = 0; a1 = 0; a2 = 0; a3 = 0; }
    return mk8((unsigned)a0, (unsigned)a1, (unsigned)a2, (unsigned)a3);
}

// ---------------- K1: x_pool = (mean_t x) @ in_W + in_b ----------------
__global__ __launch_bounds__(256) void pool_kernel(const float* __restrict__ x,
        const float* __restrict__ in_W, const float* __restrict__ in_b,
        float* __restrict__ xp){
    __shared__ float xs[512];
    __shared__ float xb[8][4];
    int tid = threadIdx.x;
    size_t base = (size_t)blockIdx.x * 512;
    xs[tid]       = x[base + tid];
    xs[tid + 256] = x[base + tid + 256];
    __syncthreads();
    if (tid < 32){
        int nl = tid >> 2, d = tid & 3;
        float s = 0.f;
        #pragma unroll
        for (int t = 0; t < 16; t++) s += xs[nl*64 + t*4 + d];
        xb[nl][d] = s * (1.f/16.f);
    }
    __syncthreads();
    int nl = tid >> 5, c = tid & 31;
    float v = in_b[c];
    #pragma unroll
    for (int d = 0; d < 4; d++) v += xb[nl][d] * in_W[d*32 + c];
    xp[(size_t)(blockIdx.x*8 + nl)*32 + c] = v;
}

// ---------------- weight -> bf16 MFMA fragments (once per launch) ----------------
__global__ void wfrag_kernel(const float* __restrict__ Wq, const float* __restrict__ Wk,
                             const float* __restrict__ Wv, const float* __restrict__ Wo,
                             unsigned short* __restrict__ frag){
    int fid = blockIdx.x, lane = threadIdx.x;
    const float* W; int b, k0, ncol;
    if (fid < 4)      { W = Wq; b = fid;      k0 = 0;  ncol = 64; }
    else if (fid < 8) { W = Wk; b = fid - 4;  k0 = 0;  ncol = 64; }
    else if (fid < 12){ W = Wv; b = fid - 8;  k0 = 0;  ncol = 64; }
    else { W = Wo; int rb = (fid-12) >> 1, ks = (fid-12) & 1; b = rb; k0 = ks*32; ncol = 32; }
    int col = 16*b + (lane & 15);
    int kk  = k0 + (lane >> 4)*8;
    unsigned short* out = frag + ((size_t)fid*64 + lane)*8;
    #pragma unroll
    for (int j = 0; j < 8; j++) out[j] = f2bf(W[(size_t)(kk + j)*ncol + col]);
}

// ---------------- CSR build ----------------
__global__ void count_kernel(const int* __restrict__ ei, int* __restrict__ counts){
    int e = blockIdx.x*256 + threadIdx.x;
    if (e >= EE) return;
    atomicAdd(&counts[ei[EE + e]], 1);
}

#define SBLK 49   // ceil(NN/1024)

// level 1: per-1024-chunk sums (coalesced int4)
__global__ __launch_bounds__(256) void bsum_kernel(const int* __restrict__ counts,
                                                   int* __restrict__ bsum){
    int b = blockIdx.x, tid = threadIdx.x;
    int base = b*1024 + tid*4;
    int s = 0;
    if (base + 3 < NN){ int4 v = *(const int4*)(counts + base); s = v.x+v.y+v.z+v.w; }
    else { for (int i = 0; i < 4; i++) if (base+i < NN) s += counts[base+i]; }
    #pragma unroll
    for (int off = 1; off < 64; off <<= 1) s += __shfl_xor(s, off, 64);
    __shared__ int wsum[4];
    if ((tid & 63) == 0) wsum[tid >> 6] = s;
    __syncthreads();
    if (tid == 0) bsum[b] = wsum[0] + wsum[1] + wsum[2] + wsum[3];
}

// level 2: per-block 1024-element scan + global offset from bsum prefix
__global__ __launch_bounds__(256) void scan2_kernel(const int* __restrict__ counts,
                                                    const int* __restrict__ bsum,
                                                    int* __restrict__ offs,
                                                    int* __restrict__ nxt){
    int b = blockIdx.x, tid = threadIdx.x;
    __shared__ int lds[256];
    __shared__ int bofs_s;
    if (tid < 64){
        int v = (tid < b) ? bsum[tid] : 0;    // SBLK=49 <= 64
        #pragma unroll
        for (int off = 1; off < 64; off <<= 1) v += __shfl_xor(v, off, 64);
        if (tid == 0) bofs_s = v;
    }
    int base = b*1024 + tid*4;
    int c0=0, c1=0, c2=0, c3=0;
    if (base + 3 < NN){ int4 v = *(const int4*)(counts + base); c0=v.x; c1=v.y; c2=v.z; c3=v.w; }
    else {
        if (base   < NN) c0 = counts[base];
        if (base+1 < NN) c1 = counts[base+1];
        if (base+2 < NN) c2 = counts[base+2];
        if (base+3 < NN) c3 = counts[base+3];
    }
    lds[tid] = c0 + c1 + c2 + c3;
    __syncthreads();
    for (int off = 1; off < 256; off <<= 1){
        int v = (tid >= off) ? lds[tid - off] : 0;
        __syncthreads();
        lds[tid] += v;
        __syncthreads();
    }
    int run = bofs_s + ((tid == 0) ? 0 : lds[tid - 1]);
    if (base   < NN){ offs[base]   = run; nxt[base]   = run; } run += c0;
    if (base+1 < NN){ offs[base+1] = run; nxt[base+1] = run; } run += c1;
    if (base+2 < NN){ offs[base+2] = run; nxt[base+2] = run; } run += c2;
    if (base+3 < NN){ offs[base+3] = run; nxt[base+3] = run; }
    if (b == 0 && tid == 0) offs[NN] = EE;   // total is statically known
}

// materialize CSR-ordered (src, weight) records -> 2-deep load chain in gat kernel
__global__ void fill_kernel(const int* __restrict__ ei, const float* __restrict__ ew,
                            int* __restrict__ nxt, int2* __restrict__ esrc){
    int e = blockIdx.x*256 + threadIdx.x;
    if (e >= EE) return;
    int dst = ei[EE + e];
    int pos = atomicAdd(&nxt[dst], 1);
    esrc[pos] = make_int2(ei[e], __float_as_int(ew[e]));
}

// ---------------- K2: xl,xr (fp16) = xp@Wl+bl, xp@Wr+br ----------------
#define LNODES 8
__global__ __launch_bounds__(128) void linlr_kernel(const float* __restrict__ xp,
        const float* __restrict__ Wl, const float* __restrict__ bl,
        const float* __restrict__ Wr, const float* __restrict__ br,
        _Float16* __restrict__ xlh, _Float16* __restrict__ xrh){
    int j = threadIdx.x;
    int n0 = blockIdx.x * LNODES;
    float wl[32], wrr[32];
    #pragma unroll
    for (int k = 0; k < 32; k++){ wl[k] = Wl[k*128 + j]; wrr[k] = Wr[k*128 + j]; }
    float blv = bl[j], brv = br[j];
    __shared__ float xs[LNODES][32];
    int r = j >> 5, c = j & 31;
    #pragma unroll
    for (int q = 0; q < LNODES/4; q++)
        xs[q*4 + r][c] = xp[(size_t)(n0 + q*4 + r)*32 + c];
    __syncthreads();
    #pragma unroll
    for (int m = 0; m < LNODES; m++){
        float al = blv, ar = brv;
        #pragma unroll
        for (int k = 0; k < 32; k++){ float v = xs[m][k]; al += v*wl[k]; ar += v*wrr[k]; }
        xlh[(size_t)(n0+m)*128 + j] = (_Float16)al;
        xrh[(size_t)(n0+m)*128 + j] = (_Float16)ar;
    }
}

// ---------------- K3: fused GATv2 edge phase, packed fp16 (h4), 8 waves/node ----------------
// 16 edges in flight per node (2 per wave x 8 waves) -> ~1 serial gather round at deg~16.
// lane: half = lane>>5 picks edge, l2 = lane&31; head = l2>>3; 4 channels/lane via h4.
// leakyrelu(m) == max(m, 0.2*m). softmax shift-invariance: |logit| small, exp() direct.
__global__ __launch_bounds__(512) void gat_fused_kernel(
        const int* __restrict__ offs, const int2* __restrict__ esrc,
        const _Float16* __restrict__ xlh, const _Float16* __restrict__ xrh,
        const float* __restrict__ We, const float* __restrict__ att,
        const float* __restrict__ bias, float* __restrict__ xq){
    int n = blockIdx.x;
    int tid = threadIdx.x;
    int w = tid >> 6, lane = tid & 63;
    int half = lane >> 5, l2 = lane & 31;
    int cb = (l2 >> 3)*32 + (l2 & 7)*4;     // channel base (4 consecutive, one head)

    h4 xr4 = __builtin_bit_cast(h4, *(const f32x2*)(xrh + (size_t)n*128 + cb));
    f32x4 wef = {We[cb], We[cb+1], We[cb+2], We[cb+3]};
    h4 We4 = {(_Float16)wef[0], (_Float16)wef[1], (_Float16)wef[2], (_Float16)wef[3]};
    f32x4 atf = {att[cb], att[cb+1], att[cb+2], att[cb+3]};
    h4 at4 = {(_Float16)atf[0], (_Float16)atf[1], (_Float16)atf[2], (_Float16)atf[3]};

    int beg = offs[n], end = offs[n+1];
    float acc0 = 0.f, acc1 = 0.f, acc2 = 0.f, acc3 = 0.f, den = 0.f;
    for (int i = beg + 2*w; i < end; i += 16){
        int e = i + half;
        bool valid = e < end;
        int ec = valid ? e : end - 1;
        int2 r = esrc[ec];
        int src  = r.x;
        float wt = __int_as_float(r.y);
        h4 xl4 = __builtin_bit_cast(h4, *(const f32x2*)(xlh + (size_t)src*128 + cb));
        h4 m = xl4 + xr4 + We4 * (_Float16)wt;
        h4 rr = __builtin_elementwise_max(m, m * (_Float16)0.2f);
        h4 zp = at4 * rr;
        float z = (float)zp[0] + (float)zp[1] + (float)zp[2] + (float)zp[3];
        z += __shfl_xor(z, 1);
        z += __shfl_xor(z, 2);
        z += __shfl_xor(z, 4);
        float a = valid ? __expf(z) : 0.f;
        den  += a;
        acc0 += a * (float)xl4[0];
        acc1 += a * (float)xl4[1];
        acc2 += a * (float)xl4[2];
        acc3 += a * (float)xl4[3];
    }
    __shared__ float lacc[8][64][4];
    __shared__ float lden[8][64];
    lacc[w][lane][0] = acc0;
    lacc[w][lane][1] = acc1;
    lacc[w][lane][2] = acc2;
    lacc[w][lane][3] = acc3;
    lden[w][lane] = den;
    __syncthreads();
    if (tid < 32){
        int j = tid;
        float s = 0.f;
        #pragma unroll
        for (int h = 0; h < 4; h++){
            int lb = h*8 + (j >> 2);
            int sub = j & 3;
            float av = 0.f, dv = 0.f;
            #pragma unroll
            for (int ww = 0; ww < 8; ww++){
                av += lacc[ww][lb][sub] + lacc[ww][lb + 32][sub];
                dv += lden[ww][lb] + lden[ww][lb + 32];
            }
            s += av / (dv + 1e-16f);
        }
        s = s*0.25f + bias[j];
        xq[(size_t)n*32 + j] = fmaxf(s, 0.f);
    }
}

// ---------------- K9: temporal attention via MFMA, one wave per node ----------------
__global__ __launch_bounds__(256) void temporal_kernel(const float* __restrict__ x,
        const float* __restrict__ xpool,
        const float* __restrict__ in_W, const float* __restrict__ in_b,
        const float* __restrict__ bq, const float* __restrict__ bk,
        const float* __restrict__ bv, const float* __restrict__ bo,
        const unsigned short* __restrict__ wfrag,
        float* __restrict__ out2){
    __shared__ float ctxL[4][64][18];   // padded: all access patterns <=2-way (free)
    int tid = threadIdx.x, w = tid >> 6, lane = tid & 63;
    int n = blockIdx.x*4 + w;
    int t = lane & 15, g = lane >> 4;
    int k0 = g * 8;

    f32x4 xv  = *(const f32x4*)(x + (size_t)n*64 + t*4);
    f32x4 ib0 = *(const f32x4*)(in_b + k0);
    f32x4 ib1 = *(const f32x4*)(in_b + k0 + 4);
    f32x4 xp0 = *(const f32x4*)(xpool + (size_t)n*32 + k0);
    f32x4 xp1 = *(const f32x4*)(xpool + (size_t)n*32 + k0 + 4);
    f32x4 iw0a = *(const f32x4*)(in_W + k0),      iw0b = *(const f32x4*)(in_W + k0 + 4);
    f32x4 iw1a = *(const f32x4*)(in_W + 32 + k0), iw1b = *(const f32x4*)(in_W + 32 + k0 + 4);
    f32x4 iw2a = *(const f32x4*)(in_W + 64 + k0), iw2b = *(const f32x4*)(in_W + 64 + k0 + 4);
    f32x4 iw3a = *(const f32x4*)(in_W + 96 + k0), iw3b = *(const f32x4*)(in_W + 96 + k0 + 4);
    f32x4 sA = ib0 + xp0 + xv[0]*iw0a + xv[1]*iw1a + xv[2]*iw2a + xv[3]*iw3a;
    f32x4 sB = ib1 + xp1 + xv[0]*iw0b + xv[1]*iw1b + xv[2]*iw2b + xv[3]*iw3b;
    bf16x8 sfrag = mk8(cvtpk(sA[0],sA[1]), cvtpk(sA[2],sA[3]), cvtpk(sB[0],sB[1]), cvtpk(sB[2],sB[3]));

    const bf16x8* WF = (const bf16x8*)wfrag;
    f32x4 zero = {0.f, 0.f, 0.f, 0.f};

    int qd0[4], qd1[4], kd0[4], kd1[4], vd0[4], vd1[4];
    #pragma unroll
    for (int b = 0; b < 4; b++){
        bf16x8 wq = WF[(0*4 + b)*64 + lane];
        bf16x8 wk = WF[(1*4 + b)*64 + lane];
        bf16x8 wv = WF[(2*4 + b)*64 + lane];
        f32x4 qc = __builtin_amdgcn_mfma_f32_16x16x32_bf16(wq, sfrag, zero, 0, 0, 0);
        f32x4 kc = __builtin_amdgcn_mfma_f32_16x16x32_bf16(wk, sfrag, zero, 0, 0, 0);
        f32x4 vc = __builtin_amdgcn_mfma_f32_16x16x32_bf16(sfrag, wv, zero, 0, 0, 0);
        f32x4 bq4 = *(const f32x4*)(bq + 16*b + 4*g);
        f32x4 bk4 = *(const f32x4*)(bk + 16*b + 4*g);
        float bvv = bv[16*b + t];
        qc += bq4; kc += bk4;
        vc[0] += bvv; vc[1] += bvv; vc[2] += bvv; vc[3] += bvv;
        qd0[b] = (int)cvtpk(qc[0], qc[1]); qd1[b] = (int)cvtpk(qc[2], qc[3]);
        kd0[b] = (int)cvtpk(kc[0], kc[1]); kd1[b] = (int)cvtpk(kc[2], kc[3]);
        vd0[b] = (int)cvtpk(vc[0], vc[1]); vd1[b] = (int)cvtpk(vc[2], vc[3]);
    }

    int s0l = t + 32*(g & 1);
    int s1l = s0l + 16;
    bool hiz = (g >= 2);
    #pragma unroll
    for (int h = 0; h < 4; h++){
        // zero only the A-operand's k>=16 slices: if A rows are 0, B there is a don't-care.
        bf16x8 ka = gather8(kd0[h], kd1[h], s0l, s1l, hiz);
        bf16x8 qb = gather8(qd0[h], qd1[h], s0l, s1l, false);
        f32x4 sc = __builtin_amdgcn_mfma_f32_16x16x32_bf16(ka, qb, zero, 0, 0, 0);
        sc *= 0.25f;
        float m = fmaxf(fmaxf(sc[0], sc[1]), fmaxf(sc[2], sc[3]));
        m = fmaxf(m, __shfl_xor(m, 16, 64));
        m = fmaxf(m, __shfl_xor(m, 32, 64));
        float p0 = __expf(sc[0] - m), p1 = __expf(sc[1] - m);
        float p2 = __expf(sc[2] - m), p3 = __expf(sc[3] - m);
        float sum = p0 + p1 + p2 + p3;
        sum += __shfl_xor(sum, 16, 64);
        sum += __shfl_xor(sum, 32, 64);
        float inv = 1.f / sum;
        int pd0 = (int)cvtpk(p0, p1), pd1 = (int)cvtpk(p2, p3);
        bf16x8 va = gather8(vd0[h], vd1[h], s0l, s1l, hiz);
        bf16x8 pb = gather8(pd0, pd1, s0l, s1l, false);
        f32x4 cx = __builtin_amdgcn_mfma_f32_16x16x32_bf16(va, pb, zero, 0, 0, 0);
        cx *= inv;
        #pragma unroll
        for (int r = 0; r < 4; r++) ctxL[w][h*16 + 4*g + r][t] = cx[r];
    }

    bf16x8 cb[2];
    #pragma unroll
    for (int ks = 0; ks < 2; ks++){
        float c0 = ctxL[w][ks*32 + k0 + 0][t], c1 = ctxL[w][ks*32 + k0 + 1][t];
        float c2 = ctxL[w][ks*32 + k0 + 2][t], c3 = ctxL[w][ks*32 + k0 + 3][t];
        float c4 = ctxL[w][ks*32 + k0 + 4][t], c5 = ctxL[w][ks*32 + k0 + 5][t];
        float c6 = ctxL[w][ks*32 + k0 + 6][t], c7 = ctxL[w][ks*32 + k0 + 7][t];
        cb[ks] = mk8(cvtpk(c0,c1), cvtpk(c2,c3), cvtpk(c4,c5), cvtpk(c6,c7));
    }
    #pragma unroll
    for (int rb = 0; rb < 2; rb++){
        bf16x8 wo0 = WF[(12 + rb*2 + 0)*64 + lane];
        bf16x8 wo1 = WF[(12 + rb*2 + 1)*64 + lane];
        f32x4 oc = __builtin_amdgcn_mfma_f32_16x16x32_bf16(wo0, cb[0], zero, 0, 0, 0);
        oc = __builtin_amdgcn_mfma_f32_16x16x32_bf16(wo1, cb[1], oc, 0, 0, 0);
        f32x4 bo4 = *(const f32x4*)(bo + 16*rb + 4*g);
        oc += bo4;
        #pragma unroll
        for (int r = 0; r < 4; r++) ctxL[w][16*rb + 4*g + r][t] = oc[r];
    }
    float o[8];
    #pragma unroll
    for (int j = 0; j < 8; j++) o[j] = ctxL[w][g*8 + j][t];
    float* outp = out2 + ((size_t)t*NN + n)*32 + g*8;
    *(f32x4*)outp       = (f32x4){o[0], o[1], o[2], o[3]};
    *((f32x4*)outp + 1) = (f32x4){o[4], o[5], o[6], o[7]};
}

// ---------------- K10: forecast / risk heads ----------------
__global__ __launch_bounds__(256) void head_kernel(const float* __restrict__ out2,
        const float* __restrict__ fW1, const float* __restrict__ fb1,
        const float* __restrict__ fW2, const float* __restrict__ fb2,
        const float* __restrict__ rW1, const float* __restrict__ rb1,
        const float* __restrict__ rW2, const float* __restrict__ rb2,
        float* __restrict__ out0, float* __restrict__ out1){
    int tid = threadIdx.x;
    int wv = tid >> 6, lane = tid & 63;
    int n = blockIdx.x*4 + wv;
    int c = lane & 31, path = lane >> 5;
    const float* W1 = path ? rW1 : fW1;
    const float* b1 = path ? rb1 : fb1;
    const float* W2 = path ? rW2 : fW2;
    const float* b2 = path ? rb2 : fb2;
    const float* last = out2 + ((size_t)15*NN + n)*32;
    float h1 = b1[c];
    #pragma unroll
    for (int k = 0; k < 32; k++) h1 += last[k] * W1[k*32 + c];
    h1 = fmaxf(h1, 0.f);
    float z = h1 * W2[c];
    #pragma unroll
    for (int off = 16; off >= 1; off >>= 1) z += __shfl_xor(z, off, 64);
    if (lane == 0)  out0[n] = fmaxf(z + b2[0], 0.f);
    if (lane == 32) out1[n] = 1.f / (1.f + __expf(-(z + b2[0])));
}

extern "C" void kernel_launch(void* const* d_in, const int* in_sizes, int n_in,
                              void* d_out, int out_size, void* d_ws, size_t ws_size,
                              hipStream_t stream){
    const float* x    = (const float*)d_in[0];
    const int*   ei   = (const int*)  d_in[1];
    const float* ew   = (const float*)d_in[2];
    const float* in_W = (const float*)d_in[3];
    const float* in_b = (const float*)d_in[4];
    const float* Wq = (const float*)d_in[19];
    const float* bq = (const float*)d_in[20];
    const float* Wk = (const float*)d_in[21];
    const float* bk = (const float*)d_in[22];
    const float* Wv = (const float*)d_in[23];
    const float* bv = (const float*)d_in[24];
    const float* Wo = (const float*)d_in[25];
    const float* bo = (const float*)d_in[26];
    const float* fW1 = (const float*)d_in[27];
    const float* fb1 = (const float*)d_in[28];
    const float* fW2 = (const float*)d_in[29];
    const float* fb2 = (const float*)d_in[30];
    const float* rW1 = (const float*)d_in[31];
    const float* rb1 = (const float*)d_in[32];
    const float* rW2 = (const float*)d_in[33];
    const float* rb2 = (const float*)d_in[34];

    float* out0 = (float*)d_out;
    float* out1 = out0 + NN;
    float* out2 = out0 + 2*NN;

    float* ws = (float*)d_ws;
    size_t off = 0;
    _Float16* xlh = (_Float16*)(ws + off); off += (size_t)NN*64;   // NN*128 fp16
    _Float16* xrh = (_Float16*)(ws + off); off += (size_t)NN*64;
    float* xpA    = ws + off; off += (size_t)NN*32;
    float* xpB    = ws + off; off += (size_t)NN*32;
    int* counts   = (int*)(ws + off); off += NN;
    int* offs     = (int*)(ws + off); off += NN + 1;
    int* nxt      = (int*)(ws + off); off += NN + 1;
    int* bsum     = (int*)(ws + off); off += SBLK;
    off = (off + 1) & ~(size_t)1;            // 8B align for int2
    int2* esrc    = (int2*)(ws + off); off += (size_t)EE*2;
    off = (off + 3) & ~(size_t)3;            // 16B align for bf16x8 loads
    unsigned short* wfrag = (unsigned short*)(ws + off); off += 16*64*8/2;

    hipMemsetAsync(counts, 0, NN*sizeof(int), stream);
    pool_kernel<<<NN/8, 256, 0, stream>>>(x, in_W, in_b, xpA);
    wfrag_kernel<<<16, 64, 0, stream>>>(Wq, Wk, Wv, Wo, wfrag);
    count_kernel<<<(EE+255)/256, 256, 0, stream>>>(ei, counts);
    bsum_kernel<<<SBLK, 256, 0, stream>>>(counts, bsum);
    scan2_kernel<<<SBLK, 256, 0, stream>>>(counts, bsum, offs, nxt);
    fill_kernel<<<(EE+255)/256, 256, 0, stream>>>(ei, ew, nxt, esrc);

    for (int layer = 0; layer < 2; layer++){
        const float* Wl   = (const float*)d_in[5 + 7*layer];
        const float* bl   = (const float*)d_in[6 + 7*layer];
        const float* Wr   = (const float*)d_in[7 + 7*layer];
        const float* br   = (const float*)d_in[8 + 7*layer];
        const float* We   = (const float*)d_in[9 + 7*layer];
        const float* att  = (const float*)d_in[10 + 7*layer];
        const float* bias = (const float*)d_in[11 + 7*layer];
        const float* xin  = layer ? xpB : xpA;
        float*       xout = layer ? xpA : xpB;
        linlr_kernel<<<NN/LNODES, 128, 0, stream>>>(xin, Wl, bl, Wr, br, xlh, xrh);
        gat_fused_kernel<<<NN, 512, 0, stream>>>(offs, esrc, xlh, xrh, We, att, bias, xout);
    }

    temporal_kernel<<<NN/4, 256, 0, stream>>>(x, xpA, in_W, in_b,
                                              bq, bk, bv, bo, wfrag, out2);
    head_kernel<<<NN/4, 256, 0, stream>>>(out2, fW1, fb1, fW2, fb2,
                                          rW1, rb1, rW2, rb2, out0, out1);
}

// Round 11
// 396.553 us; speedup vs baseline: 1.2650x; 1.2650x over previous
//
#include <hip/hip_runtime.h>
#include <hip/hip_bf16.h>

#define NN 50000
#define TT 16
#define DD 4
#define EE 800000
#define HH 4
#define HID 32
#define THID 64
#define HD 16

typedef __attribute__((ext_vector_type(8))) short bf16x8;
typedef __attribute__((ext_vector_type(4))) float f32x4;
typedef __attribute__((ext_vector_type(2))) float f32x2;
typedef __attribute__((ext_vector_type(4))) unsigned u32x4;
typedef __attribute__((ext_vector_type(4))) _Float16 h4;

__device__ __forceinline__ unsigned short f2bf(float f){
    unsigned u = __float_as_uint(f);
    u = u + 0x7fffu + ((u >> 16) & 1u);   // RNE
    return (unsigned short)(u >> 16);
}
// HW packed f32->bf16 (T12 recipe; no builtin on gfx950). Replaces ~6-op bit-math.
__device__ __forceinline__ unsigned cvtpk(float a, float b){
    unsigned r;
    asm("v_cvt_pk_bf16_f32 %0, %1, %2" : "=v"(r) : "v"(a), "v"(b));
    return r;
}
__device__ __forceinline__ bf16x8 mk8(unsigned a0, unsigned a1, unsigned a2, unsigned a3){
    u32x4 u = {a0, a1, a2, a3};
    return __builtin_bit_cast(bf16x8, u);
}
// Build an 8-bf16 operand fragment from a C-fragment's packed dword pair via 4 shfls.
__device__ __forceinline__ bf16x8 gather8(int d0, int d1, int s0, int s1, bool zero){
    int a0 = __shfl(d0, s0, 64);
    int a1 = __shfl(d1, s0, 64);
    int a2 = __shfl(d0, s1, 64);
    int a3 = __shfl(d1, s1, 64);
    if (zero){ a0 = 0; a1 = 0; a2 = 0; a3 = 0; }
    return mk8((unsigned)a0, (unsigned)a1, (unsigned)a2, (unsigned)a3);
}

// ---------------- K1: x_pool = (mean_t x) @ in_W + in_b ----------------
__global__ __launch_bounds__(256) void pool_kernel(const float* __restrict__ x,
        const float* __restrict__ in_W, const float* __restrict__ in_b,
        float* __restrict__ xp){
    __shared__ float xs[512];
    __shared__ float xb[8][4];
    int tid = threadIdx.x;
    size_t base = (size_t)blockIdx.x * 512;
    xs[tid]       = x[base + tid];
    xs[tid + 256] = x[base + tid + 256];
    __syncthreads();
    if (tid < 32){
        int nl = tid >> 2, d = tid & 3;
        float s = 0.f;
        #pragma unroll
        for (int t = 0; t < 16; t++) s += xs[nl*64 + t*4 + d];
        xb[nl][d] = s * (1.f/16.f);
    }
    __syncthreads();
    int nl = tid >> 5, c = tid & 31;
    float v = in_b[c];
    #pragma unroll
    for (int d = 0; d < 4; d++) v += xb[nl][d] * in_W[d*32 + c];
    xp[(size_t)(blockIdx.x*8 + nl)*32 + c] = v;
}

// ---------------- weight -> bf16 MFMA fragments (once per launch) ----------------
__global__ void wfrag_kernel(const float* __restrict__ Wq, const float* __restrict__ Wk,
                             const float* __restrict__ Wv, const float* __restrict__ Wo,
                             unsigned short* __restrict__ frag){
    int fid = blockIdx.x, lane = threadIdx.x;
    const float* W; int b, k0, ncol;
    if (fid < 4)      { W = Wq; b = fid;      k0 = 0;  ncol = 64; }
    else if (fid < 8) { W = Wk; b = fid - 4;  k0 = 0;  ncol = 64; }
    else if (fid < 12){ W = Wv; b = fid - 8;  k0 = 0;  ncol = 64; }
    else { W = Wo; int rb = (fid-12) >> 1, ks = (fid-12) & 1; b = rb; k0 = ks*32; ncol = 32; }
    int col = 16*b + (lane & 15);
    int kk  = k0 + (lane >> 4)*8;
    unsigned short* out = frag + ((size_t)fid*64 + lane)*8;
    #pragma unroll
    for (int j = 0; j < 8; j++) out[j] = f2bf(W[(size_t)(kk + j)*ncol + col]);
}

// ---------------- CSR build ----------------
__global__ void count_kernel(const int* __restrict__ ei, int* __restrict__ counts){
    int e = blockIdx.x*256 + threadIdx.x;
    if (e >= EE) return;
    atomicAdd(&counts[ei[EE + e]], 1);
}

#define SBLK 49   // ceil(NN/1024)

// level 1: per-1024-chunk sums (coalesced int4)
__global__ __launch_bounds__(256) void bsum_kernel(const int* __restrict__ counts,
                                                   int* __restrict__ bsum){
    int b = blockIdx.x, tid = threadIdx.x;
    int base = b*1024 + tid*4;
    int s = 0;
    if (base + 3 < NN){ int4 v = *(const int4*)(counts + base); s = v.x+v.y+v.z+v.w; }
    else { for (int i = 0; i < 4; i++) if (base+i < NN) s += counts[base+i]; }
    #pragma unroll
    for (int off = 1; off < 64; off <<= 1) s += __shfl_xor(s, off, 64);
    __shared__ int wsum[4];
    if ((tid & 63) == 0) wsum[tid >> 6] = s;
    __syncthreads();
    if (tid == 0) bsum[b] = wsum[0] + wsum[1] + wsum[2] + wsum[3];
}

// level 2: per-block 1024-element scan + global offset from bsum prefix
__global__ __launch_bounds__(256) void scan2_kernel(const int* __restrict__ counts,
                                                    const int* __restrict__ bsum,
                                                    int* __restrict__ offs,
                                                    int* __restrict__ nxt){
    int b = blockIdx.x, tid = threadIdx.x;
    __shared__ int lds[256];
    __shared__ int bofs_s;
    if (tid < 64){
        int v = (tid < b) ? bsum[tid] : 0;    // SBLK=49 <= 64
        #pragma unroll
        for (int off = 1; off < 64; off <<= 1) v += __shfl_xor(v, off, 64);
        if (tid == 0) bofs_s = v;
    }
    int base = b*1024 + tid*4;
    int c0=0, c1=0, c2=0, c3=0;
    if (base + 3 < NN){ int4 v = *(const int4*)(counts + base); c0=v.x; c1=v.y; c2=v.z; c3=v.w; }
    else {
        if (base   < NN) c0 = counts[base];
        if (base+1 < NN) c1 = counts[base+1];
        if (base+2 < NN) c2 = counts[base+2];
        if (base+3 < NN) c3 = counts[base+3];
    }
    lds[tid] = c0 + c1 + c2 + c3;
    __syncthreads();
    for (int off = 1; off < 256; off <<= 1){
        int v = (tid >= off) ? lds[tid - off] : 0;
        __syncthreads();
        lds[tid] += v;
        __syncthreads();
    }
    int run = bofs_s + ((tid == 0) ? 0 : lds[tid - 1]);
    if (base   < NN){ offs[base]   = run; nxt[base]   = run; } run += c0;
    if (base+1 < NN){ offs[base+1] = run; nxt[base+1] = run; } run += c1;
    if (base+2 < NN){ offs[base+2] = run; nxt[base+2] = run; } run += c2;
    if (base+3 < NN){ offs[base+3] = run; nxt[base+3] = run; }
    if (b == 0 && tid == 0) offs[NN] = EE;   // total is statically known
}

// materialize CSR-ordered (src, weight) records -> 2-deep load chain in gat kernel
__global__ void fill_kernel(const int* __restrict__ ei, const float* __restrict__ ew,
                            int* __restrict__ nxt, int2* __restrict__ esrc){
    int e = blockIdx.x*256 + threadIdx.x;
    if (e >= EE) return;
    int dst = ei[EE + e];
    int pos = atomicAdd(&nxt[dst], 1);
    esrc[pos] = make_int2(ei[e], __float_as_int(ew[e]));
}

// ---------------- K2: xl,xr (fp16) = xp@Wl+bl, xp@Wr+br ----------------
#define LNODES 8
__global__ __launch_bounds__(128) void linlr_kernel(const float* __restrict__ xp,
        const float* __restrict__ Wl, const float* __restrict__ bl,
        const float* __restrict__ Wr, const float* __restrict__ br,
        _Float16* __restrict__ xlh, _Float16* __restrict__ xrh){
    int j = threadIdx.x;
    int n0 = blockIdx.x * LNODES;
    float wl[32], wrr[32];
    #pragma unroll
    for (int k = 0; k < 32; k++){ wl[k] = Wl[k*128 + j]; wrr[k] = Wr[k*128 + j]; }
    float blv = bl[j], brv = br[j];
    __shared__ float xs[LNODES][32];
    int r = j >> 5, c = j & 31;
    #pragma unroll
    for (int q = 0; q < LNODES/4; q++)
        xs[q*4 + r][c] = xp[(size_t)(n0 + q*4 + r)*32 + c];
    __syncthreads();
    #pragma unroll
    for (int m = 0; m < LNODES; m++){
        float al = blv, ar = brv;
        #pragma unroll
        for (int k = 0; k < 32; k++){ float v = xs[m][k]; al += v*wl[k]; ar += v*wrr[k]; }
        xlh[(size_t)(n0+m)*128 + j] = (_Float16)al;
        xrh[(size_t)(n0+m)*128 + j] = (_Float16)ar;
    }
}

// ---------------- K3: fused GATv2 edge phase, packed fp16 (h4), 4 waves/node ----------------
// (512-thread variant regressed: occupancy 77->62%, hbm 1.1TB/s->654GB/s — per-node
//  fixed overhead doubled. 256 threads / 8 edges in flight is the sweet spot at deg~16.)
__global__ __launch_bounds__(256) void gat_fused_kernel(
        const int* __restrict__ offs, const int2* __restrict__ esrc,
        const _Float16* __restrict__ xlh, const _Float16* __restrict__ xrh,
        const float* __restrict__ We, const float* __restrict__ att,
        const float* __restrict__ bias, float* __restrict__ xq){
    int n = blockIdx.x;
    int tid = threadIdx.x;
    int w = tid >> 6, lane = tid & 63;
    int half = lane >> 5, l2 = lane & 31;
    int cb = (l2 >> 3)*32 + (l2 & 7)*4;     // channel base (4 consecutive, one head)

    h4 xr4 = __builtin_bit_cast(h4, *(const f32x2*)(xrh + (size_t)n*128 + cb));
    f32x4 wef = {We[cb], We[cb+1], We[cb+2], We[cb+3]};
    h4 We4 = {(_Float16)wef[0], (_Float16)wef[1], (_Float16)wef[2], (_Float16)wef[3]};
    f32x4 atf = {att[cb], att[cb+1], att[cb+2], att[cb+3]};
    h4 at4 = {(_Float16)atf[0], (_Float16)atf[1], (_Float16)atf[2], (_Float16)atf[3]};

    int beg = offs[n], end = offs[n+1];
    float acc0 = 0.f, acc1 = 0.f, acc2 = 0.f, acc3 = 0.f, den = 0.f;
    for (int i = beg + 2*w; i < end; i += 8){
        int e = i + half;
        bool valid = e < end;
        int ec = valid ? e : end - 1;
        int2 r = esrc[ec];
        int src  = r.x;
        float wt = __int_as_float(r.y);
        h4 xl4 = __builtin_bit_cast(h4, *(const f32x2*)(xlh + (size_t)src*128 + cb));
        h4 m = xl4 + xr4 + We4 * (_Float16)wt;
        h4 rr = __builtin_elementwise_max(m, m * (_Float16)0.2f);
        h4 zp = at4 * rr;
        float z = (float)zp[0] + (float)zp[1] + (float)zp[2] + (float)zp[3];
        z += __shfl_xor(z, 1);
        z += __shfl_xor(z, 2);
        z += __shfl_xor(z, 4);
        float a = valid ? __expf(z) : 0.f;
        den  += a;
        acc0 += a * (float)xl4[0];
        acc1 += a * (float)xl4[1];
        acc2 += a * (float)xl4[2];
        acc3 += a * (float)xl4[3];
    }
    __shared__ float lacc[4][64][4];
    __shared__ float lden[4][64];
    lacc[w][lane][0] = acc0;
    lacc[w][lane][1] = acc1;
    lacc[w][lane][2] = acc2;
    lacc[w][lane][3] = acc3;
    lden[w][lane] = den;
    __syncthreads();
    if (tid < 32){
        int j = tid;
        float s = 0.f;
        #pragma unroll
        for (int h = 0; h < 4; h++){
            int lb = h*8 + (j >> 2);
            int sub = j & 3;
            float av = 0.f, dv = 0.f;
            #pragma unroll
            for (int ww = 0; ww < 4; ww++){
                av += lacc[ww][lb][sub] + lacc[ww][lb + 32][sub];
                dv += lden[ww][lb] + lden[ww][lb + 32];
            }
            s += av / (dv + 1e-16f);
        }
        s = s*0.25f + bias[j];
        xq[(size_t)n*32 + j] = fmaxf(s, 0.f);
    }
}

// ---------------- K9: temporal attention via MFMA, one wave per node ----------------
__global__ __launch_bounds__(256) void temporal_kernel(const float* __restrict__ x,
        const float* __restrict__ xpool,
        const float* __restrict__ in_W, const float* __restrict__ in_b,
        const float* __restrict__ bq, const float* __restrict__ bk,
        const float* __restrict__ bv, const float* __restrict__ bo,
        const unsigned short* __restrict__ wfrag,
        float* __restrict__ out2){
    __shared__ float ctxL[4][64][18];   // padded: all access patterns <=2-way (free)
    int tid = threadIdx.x, w = tid >> 6, lane = tid & 63;
    int n = blockIdx.x*4 + w;
    int t = lane & 15, g = lane >> 4;
    int k0 = g * 8;

    f32x4 xv  = *(const f32x4*)(x + (size_t)n*64 + t*4);
    f32x4 ib0 = *(const f32x4*)(in_b + k0);
    f32x4 ib1 = *(const f32x4*)(in_b + k0 + 4);
    f32x4 xp0 = *(const f32x4*)(xpool + (size_t)n*32 + k0);
    f32x4 xp1 = *(const f32x4*)(xpool + (size_t)n*32 + k0 + 4);
    f32x4 iw0a = *(const f32x4*)(in_W + k0),      iw0b = *(const f32x4*)(in_W + k0 + 4);
    f32x4 iw1a = *(const f32x4*)(in_W + 32 + k0), iw1b = *(const f32x4*)(in_W + 32 + k0 + 4);
    f32x4 iw2a = *(const f32x4*)(in_W + 64 + k0), iw2b = *(const f32x4*)(in_W + 64 + k0 + 4);
    f32x4 iw3a = *(const f32x4*)(in_W + 96 + k0), iw3b = *(const f32x4*)(in_W + 96 + k0 + 4);
    f32x4 sA = ib0 + xp0 + xv[0]*iw0a + xv[1]*iw1a + xv[2]*iw2a + xv[3]*iw3a;
    f32x4 sB = ib1 + xp1 + xv[0]*iw0b + xv[1]*iw1b + xv[2]*iw2b + xv[3]*iw3b;
    bf16x8 sfrag = mk8(cvtpk(sA[0],sA[1]), cvtpk(sA[2],sA[3]), cvtpk(sB[0],sB[1]), cvtpk(sB[2],sB[3]));

    const bf16x8* WF = (const bf16x8*)wfrag;
    f32x4 zero = {0.f, 0.f, 0.f, 0.f};

    int qd0[4], qd1[4], kd0[4], kd1[4], vd0[4], vd1[4];
    #pragma unroll
    for (int b = 0; b < 4; b++){
        bf16x8 wq = WF[(0*4 + b)*64 + lane];
        bf16x8 wk = WF[(1*4 + b)*64 + lane];
        bf16x8 wv = WF[(2*4 + b)*64 + lane];
        f32x4 qc = __builtin_amdgcn_mfma_f32_16x16x32_bf16(wq, sfrag, zero, 0, 0, 0);
        f32x4 kc = __builtin_amdgcn_mfma_f32_16x16x32_bf16(wk, sfrag, zero, 0, 0, 0);
        f32x4 vc = __builtin_amdgcn_mfma_f32_16x16x32_bf16(sfrag, wv, zero, 0, 0, 0);
        f32x4 bq4 = *(const f32x4*)(bq + 16*b + 4*g);
        f32x4 bk4 = *(const f32x4*)(bk + 16*b + 4*g);
        float bvv = bv[16*b + t];
        qc += bq4; kc += bk4;
        vc[0] += bvv; vc[1] += bvv; vc[2] += bvv; vc[3] += bvv;
        qd0[b] = (int)cvtpk(qc[0], qc[1]); qd1[b] = (int)cvtpk(qc[2], qc[3]);
        kd0[b] = (int)cvtpk(kc[0], kc[1]); kd1[b] = (int)cvtpk(kc[2], kc[3]);
        vd0[b] = (int)cvtpk(vc[0], vc[1]); vd1[b] = (int)cvtpk(vc[2], vc[3]);
    }

    int s0l = t + 32*(g & 1);
    int s1l = s0l + 16;
    bool hiz = (g >= 2);
    #pragma unroll
    for (int h = 0; h < 4; h++){
        // zero only the A-operand's k>=16 slices: if A rows are 0, B there is a don't-care.
        bf16x8 ka = gather8(kd0[h], kd1[h], s0l, s1l, hiz);
        bf16x8 qb = gather8(qd0[h], qd1[h], s0l, s1l, false);
        f32x4 sc = __builtin_amdgcn_mfma_f32_16x16x32_bf16(ka, qb, zero, 0, 0, 0);
        sc *= 0.25f;
        float m = fmaxf(fmaxf(sc[0], sc[1]), fmaxf(sc[2], sc[3]));
        m = fmaxf(m, __shfl_xor(m, 16, 64));
        m = fmaxf(m, __shfl_xor(m, 32, 64));
        float p0 = __expf(sc[0] - m), p1 = __expf(sc[1] - m);
        float p2 = __expf(sc[2] - m), p3 = __expf(sc[3] - m);
        float sum = p0 + p1 + p2 + p3;
        sum += __shfl_xor(sum, 16, 64);
        sum += __shfl_xor(sum, 32, 64);
        float inv = 1.f / sum;
        int pd0 = (int)cvtpk(p0, p1), pd1 = (int)cvtpk(p2, p3);
        bf16x8 va = gather8(vd0[h], vd1[h], s0l, s1l, hiz);
        bf16x8 pb = gather8(pd0, pd1, s0l, s1l, false);
        f32x4 cx = __builtin_amdgcn_mfma_f32_16x16x32_bf16(va, pb, zero, 0, 0, 0);
        cx *= inv;
        #pragma unroll
        for (int r = 0; r < 4; r++) ctxL[w][h*16 + 4*g + r][t] = cx[r];
    }

    bf16x8 cb[2];
    #pragma unroll
    for (int ks = 0; ks < 2; ks++){
        float c0 = ctxL[w][ks*32 + k0 + 0][t], c1 = ctxL[w][ks*32 + k0 + 1][t];
        float c2 = ctxL[w][ks*32 + k0 + 2][t], c3 = ctxL[w][ks*32 + k0 + 3][t];
        float c4 = ctxL[w][ks*32 + k0 + 4][t], c5 = ctxL[w][ks*32 + k0 + 5][t];
        float c6 = ctxL[w][ks*32 + k0 + 6][t], c7 = ctxL[w][ks*32 + k0 + 7][t];
        cb[ks] = mk8(cvtpk(c0,c1), cvtpk(c2,c3), cvtpk(c4,c5), cvtpk(c6,c7));
    }
    #pragma unroll
    for (int rb = 0; rb < 2; rb++){
        bf16x8 wo0 = WF[(12 + rb*2 + 0)*64 + lane];
        bf16x8 wo1 = WF[(12 + rb*2 + 1)*64 + lane];
        f32x4 oc = __builtin_amdgcn_mfma_f32_16x16x32_bf16(wo0, cb[0], zero, 0, 0, 0);
        oc = __builtin_amdgcn_mfma_f32_16x16x32_bf16(wo1, cb[1], oc, 0, 0, 0);
        f32x4 bo4 = *(const f32x4*)(bo + 16*rb + 4*g);
        oc += bo4;
        #pragma unroll
        for (int r = 0; r < 4; r++) ctxL[w][16*rb + 4*g + r][t] = oc[r];
    }
    float o[8];
    #pragma unroll
    for (int j = 0; j < 8; j++) o[j] = ctxL[w][g*8 + j][t];
    float* outp = out2 + ((size_t)t*NN + n)*32 + g*8;
    *(f32x4*)outp       = (f32x4){o[0], o[1], o[2], o[3]};
    *((f32x4*)outp + 1) = (f32x4){o[4], o[5], o[6], o[7]};
}

// ---------------- K10: forecast / risk heads ----------------
__global__ __launch_bounds__(256) void head_kernel(const float* __restrict__ out2,
        const float* __restrict__ fW1, const float* __restrict__ fb1,
        const float* __restrict__ fW2, const float* __restrict__ fb2,
        const float* __restrict__ rW1, const float* __restrict__ rb1,
        const float* __restrict__ rW2, const float* __restrict__ rb2,
        float* __restrict__ out0, float* __restrict__ out1){
    int tid = threadIdx.x;
    int wv = tid >> 6, lane = tid & 63;
    int n = blockIdx.x*4 + wv;
    int c = lane & 31, path = lane >> 5;
    const float* W1 = path ? rW1 : fW1;
    const float* b1 = path ? rb1 : fb1;
    const float* W2 = path ? rW2 : fW2;
    const float* b2 = path ? rb2 : fb2;
    const float* last = out2 + ((size_t)15*NN + n)*32;
    float h1 = b1[c];
    #pragma unroll
    for (int k = 0; k < 32; k++) h1 += last[k] * W1[k*32 + c];
    h1 = fmaxf(h1, 0.f);
    float z = h1 * W2[c];
    #pragma unroll
    for (int off = 16; off >= 1; off >>= 1) z += __shfl_xor(z, off, 64);
    if (lane == 0)  out0[n] = fmaxf(z + b2[0], 0.f);
    if (lane == 32) out1[n] = 1.f / (1.f + __expf(-(z + b2[0])));
}

extern "C" void kernel_launch(void* const* d_in, const int* in_sizes, int n_in,
                              void* d_out, int out_size, void* d_ws, size_t ws_size,
                              hipStream_t stream){
    const float* x    = (const float*)d_in[0];
    const int*   ei   = (const int*)  d_in[1];
    const float* ew   = (const float*)d_in[2];
    const float* in_W = (const float*)d_in[3];
    const float* in_b = (const float*)d_in[4];
    const float* Wq = (const float*)d_in[19];
    const float* bq = (const float*)d_in[20];
    const float* Wk = (const float*)d_in[21];
    const float* bk = (const float*)d_in[22];
    const float* Wv = (const float*)d_in[23];
    const float* bv = (const float*)d_in[24];
    const float* Wo = (const float*)d_in[25];
    const float* bo = (const float*)d_in[26];
    const float* fW1 = (const float*)d_in[27];
    const float* fb1 = (const float*)d_in[28];
    const float* fW2 = (const float*)d_in[29];
    const float* fb2 = (const float*)d_in[30];
    const float* rW1 = (const float*)d_in[31];
    const float* rb1 = (const float*)d_in[32];
    const float* rW2 = (const float*)d_in[33];
    const float* rb2 = (const float*)d_in[34];

    float* out0 = (float*)d_out;
    float* out1 = out0 + NN;
    float* out2 = out0 + 2*NN;

    float* ws = (float*)d_ws;
    size_t off = 0;
    _Float16* xlh = (_Float16*)(ws + off); off += (size_t)NN*64;   // NN*128 fp16
    _Float16* xrh = (_Float16*)(ws + off); off += (size_t)NN*64;
    float* xpA    = ws + off; off += (size_t)NN*32;
    float* xpB    = ws + off; off += (size_t)NN*32;
    int* counts   = (int*)(ws + off); off += NN;
    int* offs     = (int*)(ws + off); off += NN + 1;
    int* nxt      = (int*)(ws + off); off += NN + 1;
    int* bsum     = (int*)(ws + off); off += SBLK;
    off = (off + 1) & ~(size_t)1;            // 8B align for int2
    int2* esrc    = (int2*)(ws + off); off += (size_t)EE*2;
    off = (off + 3) & ~(size_t)3;            // 16B align for bf16x8 loads
    unsigned short* wfrag = (unsigned short*)(ws + off); off += 16*64*8/2;

    hipMemsetAsync(counts, 0, NN*sizeof(int), stream);
    pool_kernel<<<NN/8, 256, 0, stream>>>(x, in_W, in_b, xpA);
    wfrag_kernel<<<16, 64, 0, stream>>>(Wq, Wk, Wv, Wo, wfrag);
    count_kernel<<<(EE+255)/256, 256, 0, stream>>>(ei, counts);
    bsum_kernel<<<SBLK, 256, 0, stream>>>(counts, bsum);
    scan2_kernel<<<SBLK, 256, 0, stream>>>(counts, bsum, offs, nxt);
    fill_kernel<<<(EE+255)/256, 256, 0, stream>>>(ei, ew, nxt, esrc);

    for (int layer = 0; layer < 2; layer++){
        const float* Wl   = (const float*)d_in[5 + 7*layer];
        const float* bl   = (const float*)d_in[6 + 7*layer];
        const float* Wr   = (const float*)d_in[7 + 7*layer];
        const float* br   = (const float*)d_in[8 + 7*layer];
        const float* We   = (const float*)d_in[9 + 7*layer];
        const float* att  = (const float*)d_in[10 + 7*layer];
        const float* bias = (const float*)d_in[11 + 7*layer];
        const float* xin  = layer ? xpB : xpA;
        float*       xout = layer ? xpA : xpB;
        linlr_kernel<<<NN/LNODES, 128, 0, stream>>>(xin, Wl, bl, Wr, br, xlh, xrh);
        gat_fused_kernel<<<NN, 256, 0, stream>>>(offs, esrc, xlh, xrh, We, att, bias, xout);
    }

    temporal_kernel<<<NN/4, 256, 0, stream>>>(x, xpA, in_W, in_b,
                                              bq, bk, bv, bo, wfrag, out2);
    head_kernel<<<NN/4, 256, 0, stream>>>(out2, fW1, fb1, fW2, fb2,
                                          rW1, rb1, rW2, rb2, out0, out1);
}

// Round 12
// 382.144 us; speedup vs baseline: 1.3127x; 1.0377x over previous
//
#include <hip/hip_runtime.h>
#include <hip/hip_bf16.h>

#define NN 50000
#define TT 16
#define DD 4
#define EE 800000
#define HH 4
#define HID 32
#define THID 64
#define HD 16

typedef __attribute__((ext_vector_type(8))) short bf16x8;
typedef __attribute__((ext_vector_type(4))) float f32x4;
typedef __attribute__((ext_vector_type(2))) float f32x2;
typedef __attribute__((ext_vector_type(4))) unsigned u32x4;
typedef __attribute__((ext_vector_type(4))) _Float16 h4;

__device__ __forceinline__ unsigned short f2bf(float f){
    unsigned u = __float_as_uint(f);
    u = u + 0x7fffu + ((u >> 16) & 1u);   // RNE
    return (unsigned short)(u >> 16);
}
// HW packed f32->bf16 (T12 recipe; no builtin on gfx950). Replaces ~6-op bit-math.
__device__ __forceinline__ unsigned cvtpk(float a, float b){
    unsigned r;
    asm("v_cvt_pk_bf16_f32 %0, %1, %2" : "=v"(r) : "v"(a), "v"(b));
    return r;
}
__device__ __forceinline__ bf16x8 mk8(unsigned a0, unsigned a1, unsigned a2, unsigned a3){
    u32x4 u = {a0, a1, a2, a3};
    return __builtin_bit_cast(bf16x8, u);
}
// Build an 8-bf16 operand fragment from a C-fragment's packed dword pair via 4 shfls.
__device__ __forceinline__ bf16x8 gather8(int d0, int d1, int s0, int s1, bool zero){
    int a0 = __shfl(d0, s0, 64);
    int a1 = __shfl(d1, s0, 64);
    int a2 = __shfl(d0, s1, 64);
    int a3 = __shfl(d1, s1, 64);
    if (zero){ a0 = 0; a1 = 0; a2 = 0; a3 = 0; }
    return mk8((unsigned)a0, (unsigned)a1, (unsigned)a2, (unsigned)a3);
}

// ---------------- K1: x_pool = (mean_t x) @ in_W + in_b ----------------
__global__ __launch_bounds__(256) void pool_kernel(const float* __restrict__ x,
        const float* __restrict__ in_W, const float* __restrict__ in_b,
        float* __restrict__ xp){
    __shared__ float xs[512];
    __shared__ float xb[8][4];
    int tid = threadIdx.x;
    size_t base = (size_t)blockIdx.x * 512;
    xs[tid]       = x[base + tid];
    xs[tid + 256] = x[base + tid + 256];
    __syncthreads();
    if (tid < 32){
        int nl = tid >> 2, d = tid & 3;
        float s = 0.f;
        #pragma unroll
        for (int t = 0; t < 16; t++) s += xs[nl*64 + t*4 + d];
        xb[nl][d] = s * (1.f/16.f);
    }
    __syncthreads();
    int nl = tid >> 5, c = tid & 31;
    float v = in_b[c];
    #pragma unroll
    for (int d = 0; d < 4; d++) v += xb[nl][d] * in_W[d*32 + c];
    xp[(size_t)(blockIdx.x*8 + nl)*32 + c] = v;
}

// ---------------- weight -> bf16 MFMA fragments (once per launch) ----------------
__global__ void wfrag_kernel(const float* __restrict__ Wq, const float* __restrict__ Wk,
                             const float* __restrict__ Wv, const float* __restrict__ Wo,
                             unsigned short* __restrict__ frag){
    int fid = blockIdx.x, lane = threadIdx.x;
    const float* W; int b, k0, ncol;
    if (fid < 4)      { W = Wq; b = fid;      k0 = 0;  ncol = 64; }
    else if (fid < 8) { W = Wk; b = fid - 4;  k0 = 0;  ncol = 64; }
    else if (fid < 12){ W = Wv; b = fid - 8;  k0 = 0;  ncol = 64; }
    else { W = Wo; int rb = (fid-12) >> 1, ks = (fid-12) & 1; b = rb; k0 = ks*32; ncol = 32; }
    int col = 16*b + (lane & 15);
    int kk  = k0 + (lane >> 4)*8;
    unsigned short* out = frag + ((size_t)fid*64 + lane)*8;
    #pragma unroll
    for (int j = 0; j < 8; j++) out[j] = f2bf(W[(size_t)(kk + j)*ncol + col]);
}

// ---------------- CSR build ----------------
__global__ void count_kernel(const int* __restrict__ ei, int* __restrict__ counts){
    int e = blockIdx.x*256 + threadIdx.x;
    if (e >= EE) return;
    atomicAdd(&counts[ei[EE + e]], 1);
}

#define SBLK 49   // ceil(NN/1024)

// level 1: per-1024-chunk sums (coalesced int4)
__global__ __launch_bounds__(256) void bsum_kernel(const int* __restrict__ counts,
                                                   int* __restrict__ bsum){
    int b = blockIdx.x, tid = threadIdx.x;
    int base = b*1024 + tid*4;
    int s = 0;
    if (base + 3 < NN){ int4 v = *(const int4*)(counts + base); s = v.x+v.y+v.z+v.w; }
    else { for (int i = 0; i < 4; i++) if (base+i < NN) s += counts[base+i]; }
    #pragma unroll
    for (int off = 1; off < 64; off <<= 1) s += __shfl_xor(s, off, 64);
    __shared__ int wsum[4];
    if ((tid & 63) == 0) wsum[tid >> 6] = s;
    __syncthreads();
    if (tid == 0) bsum[b] = wsum[0] + wsum[1] + wsum[2] + wsum[3];
}

// level 2: per-block 1024-element scan + global offset from bsum prefix
__global__ __launch_bounds__(256) void scan2_kernel(const int* __restrict__ counts,
                                                    const int* __restrict__ bsum,
                                                    int* __restrict__ offs,
                                                    int* __restrict__ nxt){
    int b = blockIdx.x, tid = threadIdx.x;
    __shared__ int lds[256];
    __shared__ int bofs_s;
    if (tid < 64){
        int v = (tid < b) ? bsum[tid] : 0;    // SBLK=49 <= 64
        #pragma unroll
        for (int off = 1; off < 64; off <<= 1) v += __shfl_xor(v, off, 64);
        if (tid == 0) bofs_s = v;
    }
    int base = b*1024 + tid*4;
    int c0=0, c1=0, c2=0, c3=0;
    if (base + 3 < NN){ int4 v = *(const int4*)(counts + base); c0=v.x; c1=v.y; c2=v.z; c3=v.w; }
    else {
        if (base   < NN) c0 = counts[base];
        if (base+1 < NN) c1 = counts[base+1];
        if (base+2 < NN) c2 = counts[base+2];
        if (base+3 < NN) c3 = counts[base+3];
    }
    lds[tid] = c0 + c1 + c2 + c3;
    __syncthreads();
    for (int off = 1; off < 256; off <<= 1){
        int v = (tid >= off) ? lds[tid - off] : 0;
        __syncthreads();
        lds[tid] += v;
        __syncthreads();
    }
    int run = bofs_s + ((tid == 0) ? 0 : lds[tid - 1]);
    if (base   < NN){ offs[base]   = run; nxt[base]   = run; } run += c0;
    if (base+1 < NN){ offs[base+1] = run; nxt[base+1] = run; } run += c1;
    if (base+2 < NN){ offs[base+2] = run; nxt[base+2] = run; } run += c2;
    if (base+3 < NN){ offs[base+3] = run; nxt[base+3] = run; }
    if (b == 0 && tid == 0) offs[NN] = EE;   // total is statically known
}

// materialize CSR-ordered (src, weight) records -> 2-deep load chain in gat kernel
__global__ void fill_kernel(const int* __restrict__ ei, const float* __restrict__ ew,
                            int* __restrict__ nxt, int2* __restrict__ esrc){
    int e = blockIdx.x*256 + threadIdx.x;
    if (e >= EE) return;
    int dst = ei[EE + e];
    int pos = atomicAdd(&nxt[dst], 1);
    esrc[pos] = make_int2(ei[e], __float_as_int(ew[e]));
}

// ---------------- K2: xl(fp8 e4m3), xr(fp16) = xp@Wl+bl, xp@Wr+br ----------------
// fp8 xl halves the gather row to 128B; quantization (~2e-3 abs at |xl|~0.06) is damped
// ~0.1x through the sigma~0.05 weight matrices before reaching any output.
#define LNODES 8
__global__ __launch_bounds__(128) void linlr_kernel(const float* __restrict__ xp,
        const float* __restrict__ Wl, const float* __restrict__ bl,
        const float* __restrict__ Wr, const float* __restrict__ br,
        unsigned char* __restrict__ xlf, _Float16* __restrict__ xrh){
    int j = threadIdx.x;
    int n0 = blockIdx.x * LNODES;
    float wl[32], wrr[32];
    #pragma unroll
    for (int k = 0; k < 32; k++){ wl[k] = Wl[k*128 + j]; wrr[k] = Wr[k*128 + j]; }
    float blv = bl[j], brv = br[j];
    __shared__ float xs[LNODES][32];
    int r = j >> 5, c = j & 31;
    #pragma unroll
    for (int q = 0; q < LNODES/4; q++)
        xs[q*4 + r][c] = xp[(size_t)(n0 + q*4 + r)*32 + c];
    __syncthreads();
    #pragma unroll
    for (int m = 0; m < LNODES; m++){
        float al = blv, ar = brv;
        #pragma unroll
        for (int k = 0; k < 32; k++){ float v = xs[m][k]; al += v*wl[k]; ar += v*wrr[k]; }
        unsigned p8 = __builtin_amdgcn_cvt_pk_fp8_f32(al, al, 0u, false);
        xlf[(size_t)(n0+m)*128 + j] = (unsigned char)(p8 & 0xffu);
        xrh[(size_t)(n0+m)*128 + j] = (_Float16)ar;
    }
}

// ---------------- K3: fused GATv2 edge phase, fp8 gather + packed fp16 math ----------------
// 4 waves/node, 8 edges in flight. lane: half=lane>>5 picks edge, l2=lane&31;
// 4 channels/lane. leakyrelu(m)==max(m,0.2m); |logit| small -> exp() direct.
__global__ __launch_bounds__(256) void gat_fused_kernel(
        const int* __restrict__ offs, const int2* __restrict__ esrc,
        const unsigned char* __restrict__ xlf, const _Float16* __restrict__ xrh,
        const float* __restrict__ We, const float* __restrict__ att,
        const float* __restrict__ bias, float* __restrict__ xq){
    int n = blockIdx.x;
    int tid = threadIdx.x;
    int w = tid >> 6, lane = tid & 63;
    int half = lane >> 5, l2 = lane & 31;
    int cb = (l2 >> 3)*32 + (l2 & 7)*4;     // channel base (4 consecutive, one head)

    h4 xr4 = __builtin_bit_cast(h4, *(const f32x2*)(xrh + (size_t)n*128 + cb));
    f32x4 wef = {We[cb], We[cb+1], We[cb+2], We[cb+3]};
    h4 We4 = {(_Float16)wef[0], (_Float16)wef[1], (_Float16)wef[2], (_Float16)wef[3]};
    f32x4 atf = {att[cb], att[cb+1], att[cb+2], att[cb+3]};
    h4 at4 = {(_Float16)atf[0], (_Float16)atf[1], (_Float16)atf[2], (_Float16)atf[3]};

    int beg = offs[n], end = offs[n+1];
    float acc0 = 0.f, acc1 = 0.f, acc2 = 0.f, acc3 = 0.f, den = 0.f;
    for (int i = beg + 2*w; i < end; i += 8){
        int e = i + half;
        bool valid = e < end;
        int ec = valid ? e : end - 1;
        int2 r = esrc[ec];
        int src  = r.x;
        float wt = __int_as_float(r.y);
        unsigned u = *(const unsigned*)(xlf + (size_t)src*128 + cb);
        f32x2 lo = __builtin_amdgcn_cvt_pk_f32_fp8(u, false);
        f32x2 hi = __builtin_amdgcn_cvt_pk_f32_fp8(u, true);
        h4 xl4 = {(_Float16)lo[0], (_Float16)lo[1], (_Float16)hi[0], (_Float16)hi[1]};
        h4 m = xl4 + xr4 + We4 * (_Float16)wt;
        h4 rr = __builtin_elementwise_max(m, m * (_Float16)0.2f);
        h4 zp = at4 * rr;
        float z = (float)zp[0] + (float)zp[1] + (float)zp[2] + (float)zp[3];
        z += __shfl_xor(z, 1);
        z += __shfl_xor(z, 2);
        z += __shfl_xor(z, 4);
        float a = valid ? __expf(z) : 0.f;
        den  += a;
        acc0 += a * lo[0];
        acc1 += a * lo[1];
        acc2 += a * hi[0];
        acc3 += a * hi[1];
    }
    __shared__ float lacc[4][64][4];
    __shared__ float lden[4][64];
    lacc[w][lane][0] = acc0;
    lacc[w][lane][1] = acc1;
    lacc[w][lane][2] = acc2;
    lacc[w][lane][3] = acc3;
    lden[w][lane] = den;
    __syncthreads();
    if (tid < 32){
        int j = tid;
        float s = 0.f;
        #pragma unroll
        for (int h = 0; h < 4; h++){
            int lb = h*8 + (j >> 2);
            int sub = j & 3;
            float av = 0.f, dv = 0.f;
            #pragma unroll
            for (int ww = 0; ww < 4; ww++){
                av += lacc[ww][lb][sub] + lacc[ww][lb + 32][sub];
                dv += lden[ww][lb] + lden[ww][lb + 32];
            }
            s += av / (dv + 1e-16f);
        }
        s = s*0.25f + bias[j];
        xq[(size_t)n*32 + j] = fmaxf(s, 0.f);
    }
}

// ---------------- K9: temporal attention via MFMA + fused forecast/risk heads ----------------
__global__ __launch_bounds__(256) void temporal_kernel(const float* __restrict__ x,
        const float* __restrict__ xpool,
        const float* __restrict__ in_W, const float* __restrict__ in_b,
        const float* __restrict__ bq, const float* __restrict__ bk,
        const float* __restrict__ bv, const float* __restrict__ bo,
        const unsigned short* __restrict__ wfrag,
        const float* __restrict__ fW1, const float* __restrict__ fb1,
        const float* __restrict__ fW2, const float* __restrict__ fb2,
        const float* __restrict__ rW1, const float* __restrict__ rb1,
        const float* __restrict__ rW2, const float* __restrict__ rb2,
        float* __restrict__ out0, float* __restrict__ out1,
        float* __restrict__ out2){
    __shared__ float ctxL[4][64][18];   // padded: all access patterns <=2-way (free)
    int tid = threadIdx.x, w = tid >> 6, lane = tid & 63;
    int n = blockIdx.x*4 + w;
    int t = lane & 15, g = lane >> 4;
    int k0 = g * 8;

    f32x4 xv  = *(const f32x4*)(x + (size_t)n*64 + t*4);
    f32x4 ib0 = *(const f32x4*)(in_b + k0);
    f32x4 ib1 = *(const f32x4*)(in_b + k0 + 4);
    f32x4 xp0 = *(const f32x4*)(xpool + (size_t)n*32 + k0);
    f32x4 xp1 = *(const f32x4*)(xpool + (size_t)n*32 + k0 + 4);
    f32x4 iw0a = *(const f32x4*)(in_W + k0),      iw0b = *(const f32x4*)(in_W + k0 + 4);
    f32x4 iw1a = *(const f32x4*)(in_W + 32 + k0), iw1b = *(const f32x4*)(in_W + 32 + k0 + 4);
    f32x4 iw2a = *(const f32x4*)(in_W + 64 + k0), iw2b = *(const f32x4*)(in_W + 64 + k0 + 4);
    f32x4 iw3a = *(const f32x4*)(in_W + 96 + k0), iw3b = *(const f32x4*)(in_W + 96 + k0 + 4);
    f32x4 sA = ib0 + xp0 + xv[0]*iw0a + xv[1]*iw1a + xv[2]*iw2a + xv[3]*iw3a;
    f32x4 sB = ib1 + xp1 + xv[0]*iw0b + xv[1]*iw1b + xv[2]*iw2b + xv[3]*iw3b;
    bf16x8 sfrag = mk8(cvtpk(sA[0],sA[1]), cvtpk(sA[2],sA[3]), cvtpk(sB[0],sB[1]), cvtpk(sB[2],sB[3]));

    const bf16x8* WF = (const bf16x8*)wfrag;
    f32x4 zero = {0.f, 0.f, 0.f, 0.f};

    int qd0[4], qd1[4], kd0[4], kd1[4], vd0[4], vd1[4];
    #pragma unroll
    for (int b = 0; b < 4; b++){
        bf16x8 wq = WF[(0*4 + b)*64 + lane];
        bf16x8 wk = WF[(1*4 + b)*64 + lane];
        bf16x8 wv = WF[(2*4 + b)*64 + lane];
        f32x4 qc = __builtin_amdgcn_mfma_f32_16x16x32_bf16(wq, sfrag, zero, 0, 0, 0);
        f32x4 kc = __builtin_amdgcn_mfma_f32_16x16x32_bf16(wk, sfrag, zero, 0, 0, 0);
        f32x4 vc = __builtin_amdgcn_mfma_f32_16x16x32_bf16(sfrag, wv, zero, 0, 0, 0);
        f32x4 bq4 = *(const f32x4*)(bq + 16*b + 4*g);
        f32x4 bk4 = *(const f32x4*)(bk + 16*b + 4*g);
        float bvv = bv[16*b + t];
        qc += bq4; kc += bk4;
        vc[0] += bvv; vc[1] += bvv; vc[2] += bvv; vc[3] += bvv;
        qd0[b] = (int)cvtpk(qc[0], qc[1]); qd1[b] = (int)cvtpk(qc[2], qc[3]);
        kd0[b] = (int)cvtpk(kc[0], kc[1]); kd1[b] = (int)cvtpk(kc[2], kc[3]);
        vd0[b] = (int)cvtpk(vc[0], vc[1]); vd1[b] = (int)cvtpk(vc[2], vc[3]);
    }

    int s0l = t + 32*(g & 1);
    int s1l = s0l + 16;
    bool hiz = (g >= 2);
    #pragma unroll
    for (int h = 0; h < 4; h++){
        // zero only the A-operand's k>=16 slices: if A rows are 0, B there is a don't-care.
        bf16x8 ka = gather8(kd0[h], kd1[h], s0l, s1l, hiz);
        bf16x8 qb = gather8(qd0[h], qd1[h], s0l, s1l, false);
        f32x4 sc = __builtin_amdgcn_mfma_f32_16x16x32_bf16(ka, qb, zero, 0, 0, 0);
        sc *= 0.25f;
        float m = fmaxf(fmaxf(sc[0], sc[1]), fmaxf(sc[2], sc[3]));
        m = fmaxf(m, __shfl_xor(m, 16, 64));
        m = fmaxf(m, __shfl_xor(m, 32, 64));
        float p0 = __expf(sc[0] - m), p1 = __expf(sc[1] - m);
        float p2 = __expf(sc[2] - m), p3 = __expf(sc[3] - m);
        float sum = p0 + p1 + p2 + p3;
        sum += __shfl_xor(sum, 16, 64);
        sum += __shfl_xor(sum, 32, 64);
        float inv = 1.f / sum;
        int pd0 = (int)cvtpk(p0, p1), pd1 = (int)cvtpk(p2, p3);
        bf16x8 va = gather8(vd0[h], vd1[h], s0l, s1l, hiz);
        bf16x8 pb = gather8(pd0, pd1, s0l, s1l, false);
        f32x4 cx = __builtin_amdgcn_mfma_f32_16x16x32_bf16(va, pb, zero, 0, 0, 0);
        cx *= inv;
        #pragma unroll
        for (int r = 0; r < 4; r++) ctxL[w][h*16 + 4*g + r][t] = cx[r];
    }

    bf16x8 cb[2];
    #pragma unroll
    for (int ks = 0; ks < 2; ks++){
        float c0 = ctxL[w][ks*32 + k0 + 0][t], c1 = ctxL[w][ks*32 + k0 + 1][t];
        float c2 = ctxL[w][ks*32 + k0 + 2][t], c3 = ctxL[w][ks*32 + k0 + 3][t];
        float c4 = ctxL[w][ks*32 + k0 + 4][t], c5 = ctxL[w][ks*32 + k0 + 5][t];
        float c6 = ctxL[w][ks*32 + k0 + 6][t], c7 = ctxL[w][ks*32 + k0 + 7][t];
        cb[ks] = mk8(cvtpk(c0,c1), cvtpk(c2,c3), cvtpk(c4,c5), cvtpk(c6,c7));
    }
    #pragma unroll
    for (int rb = 0; rb < 2; rb++){
        bf16x8 wo0 = WF[(12 + rb*2 + 0)*64 + lane];
        bf16x8 wo1 = WF[(12 + rb*2 + 1)*64 + lane];
        f32x4 oc = __builtin_amdgcn_mfma_f32_16x16x32_bf16(wo0, cb[0], zero, 0, 0, 0);
        oc = __builtin_amdgcn_mfma_f32_16x16x32_bf16(wo1, cb[1], oc, 0, 0, 0);
        f32x4 bo4 = *(const f32x4*)(bo + 16*rb + 4*g);
        oc += bo4;
        #pragma unroll
        for (int r = 0; r < 4; r++) ctxL[w][16*rb + 4*g + r][t] = oc[r];
    }
    float o[8];
    #pragma unroll
    for (int j = 0; j < 8; j++) o[j] = ctxL[w][g*8 + j][t];
    float* outp = out2 + ((size_t)t*NN + n)*32 + g*8;
    *(f32x4*)outp       = (f32x4){o[0], o[1], o[2], o[3]};
    *((f32x4*)outp + 1) = (f32x4){o[4], o[5], o[6], o[7]};

    // ---- fused forecast/risk heads (out^T lives in ctxL: row=channel, col=t; last=t15) ----
    int cc = lane & 31, path = lane >> 5;
    const float* W1  = path ? rW1 : fW1;
    const float* b1v = path ? rb1 : fb1;
    const float* W2  = path ? rW2 : fW2;
    const float* b2v = path ? rb2 : fb2;
    float h1 = b1v[cc];
    #pragma unroll
    for (int k = 0; k < 32; k++) h1 += ctxL[w][k][15] * W1[k*32 + cc];   // LDS broadcast reads
    h1 = fmaxf(h1, 0.f);
    float z = h1 * W2[cc];
    #pragma unroll
    for (int off2 = 16; off2 >= 1; off2 >>= 1) z += __shfl_xor(z, off2, 64);
    if (lane == 0)  out0[n] = fmaxf(z + b2v[0], 0.f);
    if (lane == 32) out1[n] = 1.f / (1.f + __expf(-(z + b2v[0])));
}

extern "C" void kernel_launch(void* const* d_in, const int* in_sizes, int n_in,
                              void* d_out, int out_size, void* d_ws, size_t ws_size,
                              hipStream_t stream){
    const float* x    = (const float*)d_in[0];
    const int*   ei   = (const int*)  d_in[1];
    const float* ew   = (const float*)d_in[2];
    const float* in_W = (const float*)d_in[3];
    const float* in_b = (const float*)d_in[4];
    const float* Wq = (const float*)d_in[19];
    const float* bq = (const float*)d_in[20];
    const float* Wk = (const float*)d_in[21];
    const float* bk = (const float*)d_in[22];
    const float* Wv = (const float*)d_in[23];
    const float* bv = (const float*)d_in[24];
    const float* Wo = (const float*)d_in[25];
    const float* bo = (const float*)d_in[26];
    const float* fW1 = (const float*)d_in[27];
    const float* fb1 = (const float*)d_in[28];
    const float* fW2 = (const float*)d_in[29];
    const float* fb2 = (const float*)d_in[30];
    const float* rW1 = (const float*)d_in[31];
    const float* rb1 = (const float*)d_in[32];
    const float* rW2 = (const float*)d_in[33];
    const float* rb2 = (const float*)d_in[34];

    float* out0 = (float*)d_out;
    float* out1 = out0 + NN;
    float* out2 = out0 + 2*NN;

    float* ws = (float*)d_ws;
    size_t off = 0;
    unsigned char* xlf = (unsigned char*)(ws + off); off += (size_t)NN*32;  // NN*128 fp8
    _Float16* xrh = (_Float16*)(ws + off); off += (size_t)NN*64;            // NN*128 fp16
    float* xpA    = ws + off; off += (size_t)NN*32;
    float* xpB    = ws + off; off += (size_t)NN*32;
    int* counts   = (int*)(ws + off); off += NN;
    int* offs     = (int*)(ws + off); off += NN + 1;
    int* nxt      = (int*)(ws + off); off += NN + 1;
    int* bsum     = (int*)(ws + off); off += SBLK;
    off = (off + 1) & ~(size_t)1;            // 8B align for int2
    int2* esrc    = (int2*)(ws + off); off += (size_t)EE*2;
    off = (off + 3) & ~(size_t)3;            // 16B align for bf16x8 loads
    unsigned short* wfrag = (unsigned short*)(ws + off); off += 16*64*8/2;

    hipMemsetAsync(counts, 0, NN*sizeof(int), stream);
    pool_kernel<<<NN/8, 256, 0, stream>>>(x, in_W, in_b, xpA);
    wfrag_kernel<<<16, 64, 0, stream>>>(Wq, Wk, Wv, Wo, wfrag);
    count_kernel<<<(EE+255)/256, 256, 0, stream>>>(ei, counts);
    bsum_kernel<<<SBLK, 256, 0, stream>>>(counts, bsum);
    scan2_kernel<<<SBLK, 256, 0, stream>>>(counts, bsum, offs, nxt);
    fill_kernel<<<(EE+255)/256, 256, 0, stream>>>(ei, ew, nxt, esrc);

    for (int layer = 0; layer < 2; layer++){
        const float* Wl   = (const float*)d_in[5 + 7*layer];
        const float* bl   = (const float*)d_in[6 + 7*layer];
        const float* Wr   = (const float*)d_in[7 + 7*layer];
        const float* br   = (const float*)d_in[8 + 7*layer];
        const float* We   = (const float*)d_in[9 + 7*layer];
        const float* att  = (const float*)d_in[10 + 7*layer];
        const float* bias = (const float*)d_in[11 + 7*layer];
        const float* xin  = layer ? xpB : xpA;
        float*       xout = layer ? xpA : xpB;
        linlr_kernel<<<NN/LNODES, 128, 0, stream>>>(xin, Wl, bl, Wr, br, xlf, xrh);
        gat_fused_kernel<<<NN, 256, 0, stream>>>(offs, esrc, xlf, xrh, We, att, bias, xout);
    }

    temporal_kernel<<<NN/4, 256, 0, stream>>>(x, xpA, in_W, in_b,
                                              bq, bk, bv, bo, wfrag,
                                              fW1, fb1, fW2, fb2, rW1, rb1, rW2, rb2,
                                              out0, out1, out2);
}

// Round 13
// 377.004 us; speedup vs baseline: 1.3306x; 1.0136x over previous
//
#include <hip/hip_runtime.h>
#include <hip/hip_bf16.h>

#define NN 50000
#define TT 16
#define DD 4
#define EE 800000
#define HH 4
#define HID 32
#define THID 64
#define HD 16

typedef __attribute__((ext_vector_type(8))) short bf16x8;
typedef __attribute__((ext_vector_type(4))) float f32x4;
typedef __attribute__((ext_vector_type(2))) float f32x2;
typedef __attribute__((ext_vector_type(4))) unsigned u32x4;
typedef __attribute__((ext_vector_type(8))) _Float16 h8;

__device__ __forceinline__ unsigned short f2bf(float f){
    unsigned u = __float_as_uint(f);
    u = u + 0x7fffu + ((u >> 16) & 1u);   // RNE
    return (unsigned short)(u >> 16);
}
// HW packed f32->bf16 (T12 recipe; no builtin on gfx950). Replaces ~6-op bit-math.
__device__ __forceinline__ unsigned cvtpk(float a, float b){
    unsigned r;
    asm("v_cvt_pk_bf16_f32 %0, %1, %2" : "=v"(r) : "v"(a), "v"(b));
    return r;
}
__device__ __forceinline__ bf16x8 mk8(unsigned a0, unsigned a1, unsigned a2, unsigned a3){
    u32x4 u = {a0, a1, a2, a3};
    return __builtin_bit_cast(bf16x8, u);
}
// Build an 8-bf16 operand fragment from a C-fragment's packed dword pair via 4 shfls.
__device__ __forceinline__ bf16x8 gather8(int d0, int d1, int s0, int s1, bool zero){
    int a0 = __shfl(d0, s0, 64);
    int a1 = __shfl(d1, s0, 64);
    int a2 = __shfl(d0, s1, 64);
    int a3 = __shfl(d1, s1, 64);
    if (zero){ a0 = 0; a1 = 0; a2 = 0; a3 = 0; }
    return mk8((unsigned)a0, (unsigned)a1, (unsigned)a2, (unsigned)a3);
}

// ---------------- prep: pool | wfrag | count fused (disjoint blockIdx ranges) ----------------
#define POOL_BLKS (NN/8)                 // 6250
#define WFRAG_BLKS 16
#define COUNT_BLKS ((EE+255)/256)        // 3125

__global__ __launch_bounds__(256) void prep_kernel(const float* __restrict__ x,
        const float* __restrict__ in_W, const float* __restrict__ in_b,
        float* __restrict__ xp,
        const float* __restrict__ Wq, const float* __restrict__ Wk,
        const float* __restrict__ Wv, const float* __restrict__ Wo,
        unsigned short* __restrict__ frag,
        const int* __restrict__ ei, int* __restrict__ counts){
    int blk = blockIdx.x;
    int tid = threadIdx.x;
    if (blk < POOL_BLKS){
        // ---- x_pool = (mean_t x) @ in_W + in_b ----
        __shared__ float xs[512];
        __shared__ float xb[8][4];
        size_t base = (size_t)blk * 512;
        xs[tid]       = x[base + tid];
        xs[tid + 256] = x[base + tid + 256];
        __syncthreads();
        if (tid < 32){
            int nl = tid >> 2, d = tid & 3;
            float s = 0.f;
            #pragma unroll
            for (int t = 0; t < 16; t++) s += xs[nl*64 + t*4 + d];
            xb[nl][d] = s * (1.f/16.f);
        }
        __syncthreads();
        int nl = tid >> 5, c = tid & 31;
        float v = in_b[c];
        #pragma unroll
        for (int d = 0; d < 4; d++) v += xb[nl][d] * in_W[d*32 + c];
        xp[(size_t)(blk*8 + nl)*32 + c] = v;
    } else if (blk < POOL_BLKS + WFRAG_BLKS){
        // ---- weight -> bf16 MFMA fragments ----
        if (tid < 64){
            int fid = blk - POOL_BLKS, lane = tid;
            const float* W; int b, k0, ncol;
            if (fid < 4)      { W = Wq; b = fid;      k0 = 0;  ncol = 64; }
            else if (fid < 8) { W = Wk; b = fid - 4;  k0 = 0;  ncol = 64; }
            else if (fid < 12){ W = Wv; b = fid - 8;  k0 = 0;  ncol = 64; }
            else { W = Wo; int rb = (fid-12) >> 1, ks = (fid-12) & 1; b = rb; k0 = ks*32; ncol = 32; }
            int col = 16*b + (lane & 15);
            int kk  = k0 + (lane >> 4)*8;
            unsigned short* out = frag + ((size_t)fid*64 + lane)*8;
            #pragma unroll
            for (int j = 0; j < 8; j++) out[j] = f2bf(W[(size_t)(kk + j)*ncol + col]);
        }
    } else {
        // ---- degree count ----
        int e = (blk - POOL_BLKS - WFRAG_BLKS)*256 + tid;
        if (e < EE) atomicAdd(&counts[ei[EE + e]], 1);
    }
}

#define SBLK 49   // ceil(NN/1024)

// level 1: per-1024-chunk sums (coalesced int4)
__global__ __launch_bounds__(256) void bsum_kernel(const int* __restrict__ counts,
                                                   int* __restrict__ bsum){
    int b = blockIdx.x, tid = threadIdx.x;
    int base = b*1024 + tid*4;
    int s = 0;
    if (base + 3 < NN){ int4 v = *(const int4*)(counts + base); s = v.x+v.y+v.z+v.w; }
    else { for (int i = 0; i < 4; i++) if (base+i < NN) s += counts[base+i]; }
    #pragma unroll
    for (int off = 1; off < 64; off <<= 1) s += __shfl_xor(s, off, 64);
    __shared__ int wsum[4];
    if ((tid & 63) == 0) wsum[tid >> 6] = s;
    __syncthreads();
    if (tid == 0) bsum[b] = wsum[0] + wsum[1] + wsum[2] + wsum[3];
}

// level 2: per-block 1024-element scan + global offset from bsum prefix
__global__ __launch_bounds__(256) void scan2_kernel(const int* __restrict__ counts,
                                                    const int* __restrict__ bsum,
                                                    int* __restrict__ offs,
                                                    int* __restrict__ nxt){
    int b = blockIdx.x, tid = threadIdx.x;
    __shared__ int lds[256];
    __shared__ int bofs_s;
    if (tid < 64){
        int v = (tid < b) ? bsum[tid] : 0;    // SBLK=49 <= 64
        #pragma unroll
        for (int off = 1; off < 64; off <<= 1) v += __shfl_xor(v, off, 64);
        if (tid == 0) bofs_s = v;
    }
    int base = b*1024 + tid*4;
    int c0=0, c1=0, c2=0, c3=0;
    if (base + 3 < NN){ int4 v = *(const int4*)(counts + base); c0=v.x; c1=v.y; c2=v.z; c3=v.w; }
    else {
        if (base   < NN) c0 = counts[base];
        if (base+1 < NN) c1 = counts[base+1];
        if (base+2 < NN) c2 = counts[base+2];
        if (base+3 < NN) c3 = counts[base+3];
    }
    lds[tid] = c0 + c1 + c2 + c3;
    __syncthreads();
    for (int off = 1; off < 256; off <<= 1){
        int v = (tid >= off) ? lds[tid - off] : 0;
        __syncthreads();
        lds[tid] += v;
        __syncthreads();
    }
    int run = bofs_s + ((tid == 0) ? 0 : lds[tid - 1]);
    if (base   < NN){ offs[base]   = run; nxt[base]   = run; } run += c0;
    if (base+1 < NN){ offs[base+1] = run; nxt[base+1] = run; } run += c1;
    if (base+2 < NN){ offs[base+2] = run; nxt[base+2] = run; } run += c2;
    if (base+3 < NN){ offs[base+3] = run; nxt[base+3] = run; }
    if (b == 0 && tid == 0) offs[NN] = EE;   // total is statically known
}

// materialize CSR-ordered (src, weight) records -> 2-deep load chain in gat kernel
__global__ void fill_kernel(const int* __restrict__ ei, const float* __restrict__ ew,
                            int* __restrict__ nxt, int2* __restrict__ esrc){
    int e = blockIdx.x*256 + threadIdx.x;
    if (e >= EE) return;
    int dst = ei[EE + e];
    int pos = atomicAdd(&nxt[dst], 1);
    esrc[pos] = make_int2(ei[e], __float_as_int(ew[e]));
}

// ---------------- K2: xl(fp8 e4m3), xr(fp16) = xp@Wl+bl, xp@Wr+br ----------------
#define LNODES 8
__global__ __launch_bounds__(128) void linlr_kernel(const float* __restrict__ xp,
        const float* __restrict__ Wl, const float* __restrict__ bl,
        const float* __restrict__ Wr, const float* __restrict__ br,
        unsigned char* __restrict__ xlf, _Float16* __restrict__ xrh){
    int j = threadIdx.x;
    int n0 = blockIdx.x * LNODES;
    float wl[32], wrr[32];
    #pragma unroll
    for (int k = 0; k < 32; k++){ wl[k] = Wl[k*128 + j]; wrr[k] = Wr[k*128 + j]; }
    float blv = bl[j], brv = br[j];
    __shared__ float xs[LNODES][32];
    int r = j >> 5, c = j & 31;
    #pragma unroll
    for (int q = 0; q < LNODES/4; q++)
        xs[q*4 + r][c] = xp[(size_t)(n0 + q*4 + r)*32 + c];
    __syncthreads();
    #pragma unroll
    for (int m = 0; m < LNODES; m++){
        float al = blv, ar = brv;
        #pragma unroll
        for (int k = 0; k < 32; k++){ float v = xs[m][k]; al += v*wl[k]; ar += v*wrr[k]; }
        unsigned p8 = __builtin_amdgcn_cvt_pk_fp8_f32(al, al, 0u, false);
        xlf[(size_t)(n0+m)*128 + j] = (unsigned char)(p8 & 0xffu);
        xrh[(size_t)(n0+m)*128 + j] = (_Float16)ar;
    }
}

// ---------------- K3: fused GATv2 edge phase v3: fp8 gather, 16 lanes/edge ----------------
// 4 edges/wave x 4 waves = 16 edges in flight -> deg~16 resolves in ONE gather round.
// lane: q=lane>>4 picks edge, l16=lane&15; 8 channels/lane (one 8B load);
// head = l16>>2 (8ch never straddles a 32ch head); logit reduce = 2 shfls over 4 lanes.
__global__ __launch_bounds__(256) void gat_fused_kernel(
        const int* __restrict__ offs, const int2* __restrict__ esrc,
        const unsigned char* __restrict__ xlf, const _Float16* __restrict__ xrh,
        const float* __restrict__ We, const float* __restrict__ att,
        const float* __restrict__ bias, float* __restrict__ xq){
    int n = blockIdx.x;
    int tid = threadIdx.x;
    int w = tid >> 6, lane = tid & 63;
    int q = lane >> 4, l16 = lane & 15;
    int cb = l16 * 8;                        // channel base (8 consecutive)

    float xr[8], Wev[8], atv[8];
    {
        f32x4 raw = *(const f32x4*)(xrh + (size_t)n*128 + cb);
        h8 x8 = __builtin_bit_cast(h8, raw);
        #pragma unroll
        for (int j = 0; j < 8; j++) xr[j] = (float)x8[j];
        f32x4 wa = *(const f32x4*)(We + cb),  wb = *(const f32x4*)(We + cb + 4);
        f32x4 aa = *(const f32x4*)(att + cb), ab = *(const f32x4*)(att + cb + 4);
        Wev[0]=wa[0]; Wev[1]=wa[1]; Wev[2]=wa[2]; Wev[3]=wa[3];
        Wev[4]=wb[0]; Wev[5]=wb[1]; Wev[6]=wb[2]; Wev[7]=wb[3];
        atv[0]=aa[0]; atv[1]=aa[1]; atv[2]=aa[2]; atv[3]=aa[3];
        atv[4]=ab[0]; atv[5]=ab[1]; atv[6]=ab[2]; atv[7]=ab[3];
    }

    int beg = offs[n], end = offs[n+1];
    float acc[8] = {0.f,0.f,0.f,0.f,0.f,0.f,0.f,0.f};
    float den = 0.f;
    for (int i = beg + 4*w; i < end; i += 16){
        int e = i + q;
        bool valid = e < end;
        int ec = valid ? e : end - 1;
        int2 r = esrc[ec];
        int src  = r.x;
        float wt = __int_as_float(r.y);
        uint2 g = *(const uint2*)(xlf + (size_t)src*128 + cb);
        f32x2 p0 = __builtin_amdgcn_cvt_pk_f32_fp8(g.x, false);
        f32x2 p1 = __builtin_amdgcn_cvt_pk_f32_fp8(g.x, true);
        f32x2 p2 = __builtin_amdgcn_cvt_pk_f32_fp8(g.y, false);
        f32x2 p3 = __builtin_amdgcn_cvt_pk_f32_fp8(g.y, true);
        float xl[8] = {p0[0],p0[1],p1[0],p1[1],p2[0],p2[1],p3[0],p3[1]};
        float z = 0.f;
        #pragma unroll
        for (int j = 0; j < 8; j++){
            float m = xl[j] + xr[j] + wt*Wev[j];
            m = m > 0.f ? m : 0.2f*m;
            z += m * atv[j];
        }
        z += __shfl_xor(z, 1);
        z += __shfl_xor(z, 2);
        float a = valid ? __expf(z) : 0.f;
        den += a;
        #pragma unroll
        for (int j = 0; j < 8; j++) acc[j] += a * xl[j];
    }
    __shared__ float lacc[4][8][64];   // transposed: stores conflict-free
    __shared__ float lden[4][64];
    #pragma unroll
    for (int j = 0; j < 8; j++) lacc[w][j][lane] = acc[j];
    lden[w][lane] = den;
    __syncthreads();
    if (tid < 32){
        float s = 0.f;
        #pragma unroll
        for (int h = 0; h < 4; h++){
            int ach = h*32 + tid;            // absolute channel
            int l = ach >> 3, j = ach & 7;
            float av = 0.f, dv = 0.f;
            #pragma unroll
            for (int ww = 0; ww < 4; ww++){
                #pragma unroll
                for (int qq = 0; qq < 4; qq++){
                    av += lacc[ww][j][qq*16 + l];
                    dv += lden[ww][qq*16 + h*4];
                }
            }
            s += av / (dv + 1e-16f);
        }
        s = s*0.25f + bias[tid];
        xq[(size_t)n*32 + tid] = fmaxf(s, 0.f);
    }
}

// ---------------- K9: temporal attention via MFMA + fused forecast/risk heads ----------------
__global__ __launch_bounds__(256) void temporal_kernel(const float* __restrict__ x,
        const float* __restrict__ xpool,
        const float* __restrict__ in_W, const float* __restrict__ in_b,
        const float* __restrict__ bq, const float* __restrict__ bk,
        const float* __restrict__ bv, const float* __restrict__ bo,
        const unsigned short* __restrict__ wfrag,
        const float* __restrict__ fW1, const float* __restrict__ fb1,
        const float* __restrict__ fW2, const float* __restrict__ fb2,
        const float* __restrict__ rW1, const float* __restrict__ rb1,
        const float* __restrict__ rW2, const float* __restrict__ rb2,
        float* __restrict__ out0, float* __restrict__ out1,
        float* __restrict__ out2){
    __shared__ float ctxL[4][64][18];   // padded: all access patterns <=2-way (free)
    int tid = threadIdx.x, w = tid >> 6, lane = tid & 63;
    int n = blockIdx.x*4 + w;
    int t = lane & 15, g = lane >> 4;
    int k0 = g * 8;

    f32x4 xv  = *(const f32x4*)(x + (size_t)n*64 + t*4);
    f32x4 ib0 = *(const f32x4*)(in_b + k0);
    f32x4 ib1 = *(const f32x4*)(in_b + k0 + 4);
    f32x4 xp0 = *(const f32x4*)(xpool + (size_t)n*32 + k0);
    f32x4 xp1 = *(const f32x4*)(xpool + (size_t)n*32 + k0 + 4);
    f32x4 iw0a = *(const f32x4*)(in_W + k0),      iw0b = *(const f32x4*)(in_W + k0 + 4);
    f32x4 iw1a = *(const f32x4*)(in_W + 32 + k0), iw1b = *(const f32x4*)(in_W + 32 + k0 + 4);
    f32x4 iw2a = *(const f32x4*)(in_W + 64 + k0), iw2b = *(const f32x4*)(in_W + 64 + k0 + 4);
    f32x4 iw3a = *(const f32x4*)(in_W + 96 + k0), iw3b = *(const f32x4*)(in_W + 96 + k0 + 4);
    f32x4 sA = ib0 + xp0 + xv[0]*iw0a + xv[1]*iw1a + xv[2]*iw2a + xv[3]*iw3a;
    f32x4 sB = ib1 + xp1 + xv[0]*iw0b + xv[1]*iw1b + xv[2]*iw2b + xv[3]*iw3b;
    bf16x8 sfrag = mk8(cvtpk(sA[0],sA[1]), cvtpk(sA[2],sA[3]), cvtpk(sB[0],sB[1]), cvtpk(sB[2],sB[3]));

    const bf16x8* WF = (const bf16x8*)wfrag;
    f32x4 zero = {0.f, 0.f, 0.f, 0.f};

    int qd0[4], qd1[4], kd0[4], kd1[4], vd0[4], vd1[4];
    #pragma unroll
    for (int b = 0; b < 4; b++){
        bf16x8 wq = WF[(0*4 + b)*64 + lane];
        bf16x8 wk = WF[(1*4 + b)*64 + lane];
        bf16x8 wv = WF[(2*4 + b)*64 + lane];
        f32x4 qc = __builtin_amdgcn_mfma_f32_16x16x32_bf16(wq, sfrag, zero, 0, 0, 0);
        f32x4 kc = __builtin_amdgcn_mfma_f32_16x16x32_bf16(wk, sfrag, zero, 0, 0, 0);
        f32x4 vc = __builtin_amdgcn_mfma_f32_16x16x32_bf16(sfrag, wv, zero, 0, 0, 0);
        f32x4 bq4 = *(const f32x4*)(bq + 16*b + 4*g);
        f32x4 bk4 = *(const f32x4*)(bk + 16*b + 4*g);
        float bvv = bv[16*b + t];
        qc += bq4; kc += bk4;
        vc[0] += bvv; vc[1] += bvv; vc[2] += bvv; vc[3] += bvv;
        qd0[b] = (int)cvtpk(qc[0], qc[1]); qd1[b] = (int)cvtpk(qc[2], qc[3]);
        kd0[b] = (int)cvtpk(kc[0], kc[1]); kd1[b] = (int)cvtpk(kc[2], kc[3]);
        vd0[b] = (int)cvtpk(vc[0], vc[1]); vd1[b] = (int)cvtpk(vc[2], vc[3]);
    }

    int s0l = t + 32*(g & 1);
    int s1l = s0l + 16;
    bool hiz = (g >= 2);
    #pragma unroll
    for (int h = 0; h < 4; h++){
        // zero only the A-operand's k>=16 slices: if A rows are 0, B there is a don't-care.
        bf16x8 ka = gather8(kd0[h], kd1[h], s0l, s1l, hiz);
        bf16x8 qb = gather8(qd0[h], qd1[h], s0l, s1l, false);
        f32x4 sc = __builtin_amdgcn_mfma_f32_16x16x32_bf16(ka, qb, zero, 0, 0, 0);
        sc *= 0.25f;
        float m = fmaxf(fmaxf(sc[0], sc[1]), fmaxf(sc[2], sc[3]));
        m = fmaxf(m, __shfl_xor(m, 16, 64));
        m = fmaxf(m, __shfl_xor(m, 32, 64));
        float p0 = __expf(sc[0] - m), p1 = __expf(sc[1] - m);
        float p2 = __expf(sc[2] - m), p3 = __expf(sc[3] - m);
        float sum = p0 + p1 + p2 + p3;
        sum += __shfl_xor(sum, 16, 64);
        sum += __shfl_xor(sum, 32, 64);
        float inv = 1.f / sum;
        int pd0 = (int)cvtpk(p0, p1), pd1 = (int)cvtpk(p2, p3);
        bf16x8 va = gather8(vd0[h], vd1[h], s0l, s1l, hiz);
        bf16x8 pb = gather8(pd0, pd1, s0l, s1l, false);
        f32x4 cx = __builtin_amdgcn_mfma_f32_16x16x32_bf16(va, pb, zero, 0, 0, 0);
        cx *= inv;
        #pragma unroll
        for (int r = 0; r < 4; r++) ctxL[w][h*16 + 4*g + r][t] = cx[r];
    }

    bf16x8 cb[2];
    #pragma unroll
    for (int ks = 0; ks < 2; ks++){
        float c0 = ctxL[w][ks*32 + k0 + 0][t], c1 = ctxL[w][ks*32 + k0 + 1][t];
        float c2 = ctxL[w][ks*32 + k0 + 2][t], c3 = ctxL[w][ks*32 + k0 + 3][t];
        float c4 = ctxL[w][ks*32 + k0 + 4][t], c5 = ctxL[w][ks*32 + k0 + 5][t];
        float c6 = ctxL[w][ks*32 + k0 + 6][t], c7 = ctxL[w][ks*32 + k0 + 7][t];
        cb[ks] = mk8(cvtpk(c0,c1), cvtpk(c2,c3), cvtpk(c4,c5), cvtpk(c6,c7));
    }
    #pragma unroll
    for (int rb = 0; rb < 2; rb++){
        bf16x8 wo0 = WF[(12 + rb*2 + 0)*64 + lane];
        bf16x8 wo1 = WF[(12 + rb*2 + 1)*64 + lane];
        f32x4 oc = __builtin_amdgcn_mfma_f32_16x16x32_bf16(wo0, cb[0], zero, 0, 0, 0);
        oc = __builtin_amdgcn_mfma_f32_16x16x32_bf16(wo1, cb[1], oc, 0, 0, 0);
        f32x4 bo4 = *(const f32x4*)(bo + 16*rb + 4*g);
        oc += bo4;
        #pragma unroll
        for (int r = 0; r < 4; r++) ctxL[w][16*rb + 4*g + r][t] = oc[r];
    }
    float o[8];
    #pragma unroll
    for (int j = 0; j < 8; j++) o[j] = ctxL[w][g*8 + j][t];
    float* outp = out2 + ((size_t)t*NN + n)*32 + g*8;
    *(f32x4*)outp       = (f32x4){o[0], o[1], o[2], o[3]};
    *((f32x4*)outp + 1) = (f32x4){o[4], o[5], o[6], o[7]};

    // ---- fused forecast/risk heads (out^T lives in ctxL: row=channel, col=t; last=t15) ----
    int cc = lane & 31, path = lane >> 5;
    const float* W1  = path ? rW1 : fW1;
    const float* b1v = path ? rb1 : fb1;
    const float* W2  = path ? rW2 : fW2;
    const float* b2v = path ? rb2 : fb2;
    float h1 = b1v[cc];
    #pragma unroll
    for (int k = 0; k < 32; k++) h1 += ctxL[w][k][15] * W1[k*32 + cc];   // LDS broadcast reads
    h1 = fmaxf(h1, 0.f);
    float z = h1 * W2[cc];
    #pragma unroll
    for (int off2 = 16; off2 >= 1; off2 >>= 1) z += __shfl_xor(z, off2, 64);
    if (lane == 0)  out0[n] = fmaxf(z + b2v[0], 0.f);
    if (lane == 32) out1[n] = 1.f / (1.f + __expf(-(z + b2v[0])));
}

extern "C" void kernel_launch(void* const* d_in, const int* in_sizes, int n_in,
                              void* d_out, int out_size, void* d_ws, size_t ws_size,
                              hipStream_t stream){
    const float* x    = (const float*)d_in[0];
    const int*   ei   = (const int*)  d_in[1];
    const float* ew   = (const float*)d_in[2];
    const float* in_W = (const float*)d_in[3];
    const float* in_b = (const float*)d_in[4];
    const float* Wq = (const float*)d_in[19];
    const float* bq = (const float*)d_in[20];
    const float* Wk = (const float*)d_in[21];
    const float* bk = (const float*)d_in[22];
    const float* Wv = (const float*)d_in[23];
    const float* bv = (const float*)d_in[24];
    const float* Wo = (const float*)d_in[25];
    const float* bo = (const float*)d_in[26];
    const float* fW1 = (const float*)d_in[27];
    const float* fb1 = (const float*)d_in[28];
    const float* fW2 = (const float*)d_in[29];
    const float* fb2 = (const float*)d_in[30];
    const float* rW1 = (const float*)d_in[31];
    const float* rb1 = (const float*)d_in[32];
    const float* rW2 = (const float*)d_in[33];
    const float* rb2 = (const float*)d_in[34];

    float* out0 = (float*)d_out;
    float* out1 = out0 + NN;
    float* out2 = out0 + 2*NN;

    float* ws = (float*)d_ws;
    size_t off = 0;
    unsigned char* xlf = (unsigned char*)(ws + off); off += (size_t)NN*32;  // NN*128 fp8
    _Float16* xrh = (_Float16*)(ws + off); off += (size_t)NN*64;            // NN*128 fp16
    float* xpA    = ws + off; off += (size_t)NN*32;
    float* xpB    = ws + off; off += (size_t)NN*32;
    int* counts   = (int*)(ws + off); off += NN;
    int* offs     = (int*)(ws + off); off += NN + 1;
    int* nxt      = (int*)(ws + off); off += NN + 1;
    int* bsum     = (int*)(ws + off); off += SBLK;
    off = (off + 1) & ~(size_t)1;            // 8B align for int2
    int2* esrc    = (int2*)(ws + off); off += (size_t)EE*2;
    off = (off + 3) & ~(size_t)3;            // 16B align for bf16x8 loads
    unsigned short* wfrag = (unsigned short*)(ws + off); off += 16*64*8/2;

    hipMemsetAsync(counts, 0, NN*sizeof(int), stream);
    prep_kernel<<<POOL_BLKS + WFRAG_BLKS + COUNT_BLKS, 256, 0, stream>>>(
        x, in_W, in_b, xpA, Wq, Wk, Wv, Wo, wfrag, ei, counts);
    bsum_kernel<<<SBLK, 256, 0, stream>>>(counts, bsum);
    scan2_kernel<<<SBLK, 256, 0, stream>>>(counts, bsum, offs, nxt);
    fill_kernel<<<(EE+255)/256, 256, 0, stream>>>(ei, ew, nxt, esrc);

    for (int layer = 0; layer < 2; layer++){
        const float* Wl   = (const float*)d_in[5 + 7*layer];
        const float* bl   = (const float*)d_in[6 + 7*layer];
        const float* Wr   = (const float*)d_in[7 + 7*layer];
        const float* br   = (const float*)d_in[8 + 7*layer];
        const float* We   = (const float*)d_in[9 + 7*layer];
        const float* att  = (const float*)d_in[10 + 7*layer];
        const float* bias = (const float*)d_in[11 + 7*layer];
        const float* xin  = layer ? xpB : xpA;
        float*       xout = layer ? xpA : xpB;
        linlr_kernel<<<NN/LNODES, 128, 0, stream>>>(xin, Wl, bl, Wr, br, xlf, xrh);
        gat_fused_kernel<<<NN, 256, 0, stream>>>(offs, esrc, xlf, xrh, We, att, bias, xout);
    }

    temporal_kernel<<<NN/4, 256, 0, stream>>>(x, xpA, in_W, in_b,
                                              bq, bk, bv, bo, wfrag,
                                              fW1, fb1, fW2, fb2, rW1, rb1, rW2, rb2,
                                              out0, out1, out2);
}

// Round 15
// 376.183 us; speedup vs baseline: 1.3335x; 1.0022x over previous
//
#include <hip/hip_runtime.h>
#include <hip/hip_bf16.h>

#define NN 50000
#define TT 16
#define DD 4
#define EE 800000
#define HH 4
#define HID 32
#define THID 64
#define HD 16

typedef __attribute__((ext_vector_type(8))) short bf16x8;
typedef __attribute__((ext_vector_type(4))) short bf16x4;
typedef __attribute__((ext_vector_type(4))) float f32x4;
typedef __attribute__((ext_vector_type(2))) float f32x2;
typedef __attribute__((ext_vector_type(4))) unsigned u32x4;
typedef __attribute__((ext_vector_type(2))) unsigned u32x2;
typedef __attribute__((ext_vector_type(8))) _Float16 h8;

__device__ __forceinline__ unsigned short f2bf(float f){
    unsigned u = __float_as_uint(f);
    u = u + 0x7fffu + ((u >> 16) & 1u);   // RNE
    return (unsigned short)(u >> 16);
}
// HW packed f32->bf16 (T12 recipe; no builtin on gfx950). Replaces ~6-op bit-math.
__device__ __forceinline__ unsigned cvtpk(float a, float b){
    unsigned r;
    asm("v_cvt_pk_bf16_f32 %0, %1, %2" : "=v"(r) : "v"(a), "v"(b));
    return r;
}
__device__ __forceinline__ bf16x8 mk8(unsigned a0, unsigned a1, unsigned a2, unsigned a3){
    u32x4 u = {a0, a1, a2, a3};
    return __builtin_bit_cast(bf16x8, u);
}
__device__ __forceinline__ bf16x4 mk4(unsigned a0, unsigned a1){
    u32x2 u = {a0, a1};
    return __builtin_bit_cast(bf16x4, u);
}
// 16x16x16 bf16 MFMA (K=16, 2-VGPR A/B). C-fragment layout == A/B operand layout
// lane-for-lane, so C-frag dword pairs feed the next MFMA with ZERO shuffles.
// Inline asm is opaque to the compiler's MFMA hazard recognizer -> must be
// self-contained: "=&v" early-clobber (D must not alias A/B) + s_nop padding
// (VALU-write->MFMA-read = 2 cyc before; MFMA-write->VALU-read <= 16 cyc after).
__device__ __forceinline__ f32x4 mfma16(bf16x4 a, bf16x4 b, f32x4 c){
    f32x4 d;
    asm volatile("s_nop 1\n\t"
                 "v_mfma_f32_16x16x16_bf16 %0, %1, %2, %3\n\t"
                 "s_nop 7\n\t"
                 "s_nop 7"
                 : "=&v"(d) : "v"(a), "v"(b), "v"(c));
    return d;
}

// ---------------- prep: pool | wfrag | count fused (disjoint blockIdx ranges) ----------------
#define POOL_BLKS (NN/8)                 // 6250
#define WFRAG_BLKS 16
#define COUNT_BLKS ((EE+255)/256)        // 3125

__global__ __launch_bounds__(256) void prep_kernel(const float* __restrict__ x,
        const float* __restrict__ in_W, const float* __restrict__ in_b,
        float* __restrict__ xp,
        const float* __restrict__ Wq, const float* __restrict__ Wk,
        const float* __restrict__ Wv, const float* __restrict__ Wo,
        unsigned short* __restrict__ frag,
        const int* __restrict__ ei, int* __restrict__ counts){
    int blk = blockIdx.x;
    int tid = threadIdx.x;
    if (blk < POOL_BLKS){
        __shared__ float xs[512];
        __shared__ float xb[8][4];
        size_t base = (size_t)blk * 512;
        xs[tid]       = x[base + tid];
        xs[tid + 256] = x[base + tid + 256];
        __syncthreads();
        if (tid < 32){
            int nl = tid >> 2, d = tid & 3;
            float s = 0.f;
            #pragma unroll
            for (int t = 0; t < 16; t++) s += xs[nl*64 + t*4 + d];
            xb[nl][d] = s * (1.f/16.f);
        }
        __syncthreads();
        int nl = tid >> 5, c = tid & 31;
        float v = in_b[c];
        #pragma unroll
        for (int d = 0; d < 4; d++) v += xb[nl][d] * in_W[d*32 + c];
        xp[(size_t)(blk*8 + nl)*32 + c] = v;
    } else if (blk < POOL_BLKS + WFRAG_BLKS){
        if (tid < 64){
            int fid = blk - POOL_BLKS, lane = tid;
            const float* W; int b, k0, ncol;
            if (fid < 4)      { W = Wq; b = fid;      k0 = 0;  ncol = 64; }
            else if (fid < 8) { W = Wk; b = fid - 4;  k0 = 0;  ncol = 64; }
            else if (fid < 12){ W = Wv; b = fid - 8;  k0 = 0;  ncol = 64; }
            else { W = Wo; int rb = (fid-12) >> 1, ks = (fid-12) & 1; b = rb; k0 = ks*32; ncol = 32; }
            int col = 16*b + (lane & 15);
            int kk  = k0 + (lane >> 4)*8;
            unsigned short* out = frag + ((size_t)fid*64 + lane)*8;
            #pragma unroll
            for (int j = 0; j < 8; j++) out[j] = f2bf(W[(size_t)(kk + j)*ncol + col]);
        }
    } else {
        int e = (blk - POOL_BLKS - WFRAG_BLKS)*256 + tid;
        if (e < EE) atomicAdd(&counts[ei[EE + e]], 1);
    }
}

#define SBLK 49   // ceil(NN/1024)

__global__ __launch_bounds__(256) void bsum_kernel(const int* __restrict__ counts,
                                                   int* __restrict__ bsum){
    int b = blockIdx.x, tid = threadIdx.x;
    int base = b*1024 + tid*4;
    int s = 0;
    if (base + 3 < NN){ int4 v = *(const int4*)(counts + base); s = v.x+v.y+v.z+v.w; }
    else { for (int i = 0; i < 4; i++) if (base+i < NN) s += counts[base+i]; }
    #pragma unroll
    for (int off = 1; off < 64; off <<= 1) s += __shfl_xor(s, off, 64);
    __shared__ int wsum[4];
    if ((tid & 63) == 0) wsum[tid >> 6] = s;
    __syncthreads();
    if (tid == 0) bsum[b] = wsum[0] + wsum[1] + wsum[2] + wsum[3];
}

__global__ __launch_bounds__(256) void scan2_kernel(const int* __restrict__ counts,
                                                    const int* __restrict__ bsum,
                                                    int* __restrict__ offs,
                                                    int* __restrict__ nxt){
    int b = blockIdx.x, tid = threadIdx.x;
    __shared__ int lds[256];
    __shared__ int bofs_s;
    if (tid < 64){
        int v = (tid < b) ? bsum[tid] : 0;    // SBLK=49 <= 64
        #pragma unroll
        for (int off = 1; off < 64; off <<= 1) v += __shfl_xor(v, off, 64);
        if (tid == 0) bofs_s = v;
    }
    int base = b*1024 + tid*4;
    int c0=0, c1=0, c2=0, c3=0;
    if (base + 3 < NN){ int4 v = *(const int4*)(counts + base); c0=v.x; c1=v.y; c2=v.z; c3=v.w; }
    else {
        if (base   < NN) c0 = counts[base];
        if (base+1 < NN) c1 = counts[base+1];
        if (base+2 < NN) c2 = counts[base+2];
        if (base+3 < NN) c3 = counts[base+3];
    }
    lds[tid] = c0 + c1 + c2 + c3;
    __syncthreads();
    for (int off = 1; off < 256; off <<= 1){
        int v = (tid >= off) ? lds[tid - off] : 0;
        __syncthreads();
        lds[tid] += v;
        __syncthreads();
    }
    int run = bofs_s + ((tid == 0) ? 0 : lds[tid - 1]);
    if (base   < NN){ offs[base]   = run; nxt[base]   = run; } run += c0;
    if (base+1 < NN){ offs[base+1] = run; nxt[base+1] = run; } run += c1;
    if (base+2 < NN){ offs[base+2] = run; nxt[base+2] = run; } run += c2;
    if (base+3 < NN){ offs[base+3] = run; nxt[base+3] = run; }
    if (b == 0 && tid == 0) offs[NN] = EE;   // total is statically known
}

__global__ void fill_kernel(const int* __restrict__ ei, const float* __restrict__ ew,
                            int* __restrict__ nxt, int2* __restrict__ esrc){
    int e = blockIdx.x*256 + threadIdx.x;
    if (e >= EE) return;
    int dst = ei[EE + e];
    int pos = atomicAdd(&nxt[dst], 1);
    esrc[pos] = make_int2(ei[e], __float_as_int(ew[e]));
}

// ---------------- K2: xl(fp8 e4m3), xr(fp16) = xp@Wl+bl, xp@Wr+br ----------------
#define LNODES 16
__global__ __launch_bounds__(128) void linlr_kernel(const float* __restrict__ xp,
        const float* __restrict__ Wl, const float* __restrict__ bl,
        const float* __restrict__ Wr, const float* __restrict__ br,
        unsigned char* __restrict__ xlf, _Float16* __restrict__ xrh){
    int j = threadIdx.x;
    int n0 = blockIdx.x * LNODES;
    float wl[32], wrr[32];
    #pragma unroll
    for (int k = 0; k < 32; k++){ wl[k] = Wl[k*128 + j]; wrr[k] = Wr[k*128 + j]; }
    float blv = bl[j], brv = br[j];
    __shared__ float xs[LNODES][32];
    int r = j >> 5, c = j & 31;
    #pragma unroll
    for (int q = 0; q < LNODES/4; q++)
        xs[q*4 + r][c] = xp[(size_t)(n0 + q*4 + r)*32 + c];
    __syncthreads();
    #pragma unroll
    for (int m = 0; m < LNODES; m++){
        float al = blv, ar = brv;
        #pragma unroll
        for (int k = 0; k < 32; k++){ float v = xs[m][k]; al += v*wl[k]; ar += v*wrr[k]; }
        unsigned p8 = __builtin_amdgcn_cvt_pk_fp8_f32(al, al, 0u, false);
        xlf[(size_t)(n0+m)*128 + j] = (unsigned char)(p8 & 0xffu);
        xrh[(size_t)(n0+m)*128 + j] = (_Float16)ar;
    }
}

// ---------------- K3: fused GATv2 edge phase v3: fp8 gather, 16 lanes/edge ----------------
__global__ __launch_bounds__(256) void gat_fused_kernel(
        const int* __restrict__ offs, const int2* __restrict__ esrc,
        const unsigned char* __restrict__ xlf, const _Float16* __restrict__ xrh,
        const float* __restrict__ We, const float* __restrict__ att,
        const float* __restrict__ bias, float* __restrict__ xq){
    int n = blockIdx.x;
    int tid = threadIdx.x;
    int w = tid >> 6, lane = tid & 63;
    int q = lane >> 4, l16 = lane & 15;
    int cb = l16 * 8;                        // channel base (8 consecutive)

    float xr[8], Wev[8], atv[8];
    {
        f32x4 raw = *(const f32x4*)(xrh + (size_t)n*128 + cb);
        h8 x8 = __builtin_bit_cast(h8, raw);
        #pragma unroll
        for (int j = 0; j < 8; j++) xr[j] = (float)x8[j];
        f32x4 wa = *(const f32x4*)(We + cb),  wb = *(const f32x4*)(We + cb + 4);
        f32x4 aa = *(const f32x4*)(att + cb), ab = *(const f32x4*)(att + cb + 4);
        Wev[0]=wa[0]; Wev[1]=wa[1]; Wev[2]=wa[2]; Wev[3]=wa[3];
        Wev[4]=wb[0]; Wev[5]=wb[1]; Wev[6]=wb[2]; Wev[7]=wb[3];
        atv[0]=aa[0]; atv[1]=aa[1]; atv[2]=aa[2]; atv[3]=aa[3];
        atv[4]=ab[0]; atv[5]=ab[1]; atv[6]=ab[2]; atv[7]=ab[3];
    }

    int beg = offs[n], end = offs[n+1];
    float acc[8] = {0.f,0.f,0.f,0.f,0.f,0.f,0.f,0.f};
    float den = 0.f;
    for (int i = beg + 4*w; i < end; i += 16){
        int e = i + q;
        bool valid = e < end;
        int ec = valid ? e : end - 1;
        int2 r = esrc[ec];
        int src  = r.x;
        float wt = __int_as_float(r.y);
        uint2 g = *(const uint2*)(xlf + (size_t)src*128 + cb);
        f32x2 p0 = __builtin_amdgcn_cvt_pk_f32_fp8(g.x, false);
        f32x2 p1 = __builtin_amdgcn_cvt_pk_f32_fp8(g.x, true);
        f32x2 p2 = __builtin_amdgcn_cvt_pk_f32_fp8(g.y, false);
        f32x2 p3 = __builtin_amdgcn_cvt_pk_f32_fp8(g.y, true);
        float xl[8] = {p0[0],p0[1],p1[0],p1[1],p2[0],p2[1],p3[0],p3[1]};
        float z = 0.f;
        #pragma unroll
        for (int j = 0; j < 8; j++){
            float m = xl[j] + xr[j] + wt*Wev[j];
            m = m > 0.f ? m : 0.2f*m;
            z += m * atv[j];
        }
        z += __shfl_xor(z, 1);
        z += __shfl_xor(z, 2);
        float a = valid ? __expf(z) : 0.f;
        den += a;
        #pragma unroll
        for (int j = 0; j < 8; j++) acc[j] += a * xl[j];
    }
    __shared__ float lacc[4][8][64];   // transposed: stores conflict-free
    __shared__ float lden[4][64];
    #pragma unroll
    for (int j = 0; j < 8; j++) lacc[w][j][lane] = acc[j];
    lden[w][lane] = den;
    __syncthreads();
    if (tid < 32){
        float s = 0.f;
        #pragma unroll
        for (int h = 0; h < 4; h++){
            int ach = h*32 + tid;            // absolute channel
            int l = ach >> 3, j = ach & 7;
            float av = 0.f, dv = 0.f;
            #pragma unroll
            for (int ww = 0; ww < 4; ww++){
                #pragma unroll
                for (int qq = 0; qq < 4; qq++){
                    av += lacc[ww][j][qq*16 + l];
                    dv += lden[ww][qq*16 + h*4];
                }
            }
            s += av / (dv + 1e-16f);
        }
        s = s*0.25f + bias[tid];
        xq[(size_t)n*32 + tid] = fmaxf(s, 0.f);
    }
}

// ---------------- K9: temporal attention via MFMA + fused forecast/risk heads ----------------
// C-fragment (col=lane&15,row=4*(lane>>4)+reg) == 16x16x16 A/B operand layout lane-for-lane
// -> scores and PV MFMAs consume prior C-fragments DIRECTLY (zero shuffles, K=16 exact).
__global__ __launch_bounds__(256) void temporal_kernel(const float* __restrict__ x,
        const float* __restrict__ xpool,
        const float* __restrict__ in_W, const float* __restrict__ in_b,
        const float* __restrict__ bq, const float* __restrict__ bk,
        const float* __restrict__ bv, const float* __restrict__ bo,
        const unsigned short* __restrict__ wfrag,
        const float* __restrict__ fW1, const float* __restrict__ fb1,
        const float* __restrict__ fW2, const float* __restrict__ fb2,
        const float* __restrict__ rW1, const float* __restrict__ rb1,
        const float* __restrict__ rW2, const float* __restrict__ rb2,
        float* __restrict__ out0, float* __restrict__ out1,
        float* __restrict__ out2){
    __shared__ float ctxL[4][64][18];   // padded: all access patterns <=2-way (free)
    int tid = threadIdx.x, w = tid >> 6, lane = tid & 63;
    int n = blockIdx.x*4 + w;
    int t = lane & 15, g = lane >> 4;
    int k0 = g * 8;

    f32x4 xv  = *(const f32x4*)(x + (size_t)n*64 + t*4);
    f32x4 ib0 = *(const f32x4*)(in_b + k0);
    f32x4 ib1 = *(const f32x4*)(in_b + k0 + 4);
    f32x4 xp0 = *(const f32x4*)(xpool + (size_t)n*32 + k0);
    f32x4 xp1 = *(const f32x4*)(xpool + (size_t)n*32 + k0 + 4);
    f32x4 iw0a = *(const f32x4*)(in_W + k0),      iw0b = *(const f32x4*)(in_W + k0 + 4);
    f32x4 iw1a = *(const f32x4*)(in_W + 32 + k0), iw1b = *(const f32x4*)(in_W + 32 + k0 + 4);
    f32x4 iw2a = *(const f32x4*)(in_W + 64 + k0), iw2b = *(const f32x4*)(in_W + 64 + k0 + 4);
    f32x4 iw3a = *(const f32x4*)(in_W + 96 + k0), iw3b = *(const f32x4*)(in_W + 96 + k0 + 4);
    f32x4 sA = ib0 + xp0 + xv[0]*iw0a + xv[1]*iw1a + xv[2]*iw2a + xv[3]*iw3a;
    f32x4 sB = ib1 + xp1 + xv[0]*iw0b + xv[1]*iw1b + xv[2]*iw2b + xv[3]*iw3b;
    bf16x8 sfrag = mk8(cvtpk(sA[0],sA[1]), cvtpk(sA[2],sA[3]), cvtpk(sB[0],sB[1]), cvtpk(sB[2],sB[3]));

    const bf16x8* WF = (const bf16x8*)wfrag;
    f32x4 zero = {0.f, 0.f, 0.f, 0.f};

    unsigned qd0[4], qd1[4], kd0[4], kd1[4], vd0[4], vd1[4];
    #pragma unroll
    for (int b = 0; b < 4; b++){
        bf16x8 wq = WF[(0*4 + b)*64 + lane];
        bf16x8 wk = WF[(1*4 + b)*64 + lane];
        bf16x8 wv = WF[(2*4 + b)*64 + lane];
        f32x4 qc = __builtin_amdgcn_mfma_f32_16x16x32_bf16(wq, sfrag, zero, 0, 0, 0);
        f32x4 kc = __builtin_amdgcn_mfma_f32_16x16x32_bf16(wk, sfrag, zero, 0, 0, 0);
        f32x4 vc = __builtin_amdgcn_mfma_f32_16x16x32_bf16(sfrag, wv, zero, 0, 0, 0);
        f32x4 bq4 = *(const f32x4*)(bq + 16*b + 4*g);
        f32x4 bk4 = *(const f32x4*)(bk + 16*b + 4*g);
        float bvv = bv[16*b + t];
        qc += bq4; kc += bk4;
        vc[0] += bvv; vc[1] += bvv; vc[2] += bvv; vc[3] += bvv;
        qd0[b] = cvtpk(qc[0], qc[1]); qd1[b] = cvtpk(qc[2], qc[3]);
        kd0[b] = cvtpk(kc[0], kc[1]); kd1[b] = cvtpk(kc[2], kc[3]);
        vd0[b] = cvtpk(vc[0], vc[1]); vd1[b] = cvtpk(vc[2], vc[3]);
    }

    #pragma unroll
    for (int h = 0; h < 4; h++){
        f32x4 sc = mfma16(mk4(kd0[h], kd1[h]), mk4(qd0[h], qd1[h]), zero);
        sc *= 0.25f;
        float m = fmaxf(fmaxf(sc[0], sc[1]), fmaxf(sc[2], sc[3]));
        m = fmaxf(m, __shfl_xor(m, 16, 64));
        m = fmaxf(m, __shfl_xor(m, 32, 64));
        float p0 = __expf(sc[0] - m), p1 = __expf(sc[1] - m);
        float p2 = __expf(sc[2] - m), p3 = __expf(sc[3] - m);
        float sum = p0 + p1 + p2 + p3;
        sum += __shfl_xor(sum, 16, 64);
        sum += __shfl_xor(sum, 32, 64);
        float inv = 1.f / sum;
        f32x4 cx = mfma16(mk4(vd0[h], vd1[h]), mk4(cvtpk(p0, p1), cvtpk(p2, p3)), zero);
        cx *= inv;
        #pragma unroll
        for (int r = 0; r < 4; r++) ctxL[w][h*16 + 4*g + r][t] = cx[r];
    }

    bf16x8 cbf[2];
    #pragma unroll
    for (int ks = 0; ks < 2; ks++){
        float c0 = ctxL[w][ks*32 + k0 + 0][t], c1 = ctxL[w][ks*32 + k0 + 1][t];
        float c2 = ctxL[w][ks*32 + k0 + 2][t], c3 = ctxL[w][ks*32 + k0 + 3][t];
        float c4 = ctxL[w][ks*32 + k0 + 4][t], c5 = ctxL[w][ks*32 + k0 + 5][t];
        float c6 = ctxL[w][ks*32 + k0 + 6][t], c7 = ctxL[w][ks*32 + k0 + 7][t];
        cbf[ks] = mk8(cvtpk(c0,c1), cvtpk(c2,c3), cvtpk(c4,c5), cvtpk(c6,c7));
    }
    #pragma unroll
    for (int rb = 0; rb < 2; rb++){
        bf16x8 wo0 = WF[(12 + rb*2 + 0)*64 + lane];
        bf16x8 wo1 = WF[(12 + rb*2 + 1)*64 + lane];
        f32x4 oc = __builtin_amdgcn_mfma_f32_16x16x32_bf16(wo0, cbf[0], zero, 0, 0, 0);
        oc = __builtin_amdgcn_mfma_f32_16x16x32_bf16(wo1, cbf[1], oc, 0, 0, 0);
        f32x4 bo4 = *(const f32x4*)(bo + 16*rb + 4*g);
        oc += bo4;
        #pragma unroll
        for (int r = 0; r < 4; r++) ctxL[w][16*rb + 4*g + r][t] = oc[r];
    }
    float o[8];
    #pragma unroll
    for (int j = 0; j < 8; j++) o[j] = ctxL[w][g*8 + j][t];
    float* outp = out2 + ((size_t)t*NN + n)*32 + g*8;
    *(f32x4*)outp       = (f32x4){o[0], o[1], o[2], o[3]};
    *((f32x4*)outp + 1) = (f32x4){o[4], o[5], o[6], o[7]};

    // ---- fused forecast/risk heads (out^T lives in ctxL: row=channel, col=t; last=t15) ----
    int cc = lane & 31, path = lane >> 5;
    const float* W1  = path ? rW1 : fW1;
    const float* b1v = path ? rb1 : fb1;
    const float* W2  = path ? rW2 : fW2;
    const float* b2v = path ? rb2 : fb2;
    float h1 = b1v[cc];
    #pragma unroll
    for (int k = 0; k < 32; k++) h1 += ctxL[w][k][15] * W1[k*32 + cc];   // LDS broadcast reads
    h1 = fmaxf(h1, 0.f);
    float z = h1 * W2[cc];
    #pragma unroll
    for (int off2 = 16; off2 >= 1; off2 >>= 1) z += __shfl_xor(z, off2, 64);
    if (lane == 0)  out0[n] = fmaxf(z + b2v[0], 0.f);
    if (lane == 32) out1[n] = 1.f / (1.f + __expf(-(z + b2v[0])));
}

extern "C" void kernel_launch(void* const* d_in, const int* in_sizes, int n_in,
                              void* d_out, int out_size, void* d_ws, size_t ws_size,
                              hipStream_t stream){
    const float* x    = (const float*)d_in[0];
    const int*   ei   = (const int*)  d_in[1];
    const float* ew   = (const float*)d_in[2];
    const float* in_W = (const float*)d_in[3];
    const float* in_b = (const float*)d_in[4];
    const float* Wq = (const float*)d_in[19];
    const float* bq = (const float*)d_in[20];
    const float* Wk = (const float*)d_in[21];
    const float* bk = (const float*)d_in[22];
    const float* Wv = (const float*)d_in[23];
    const float* bv = (const float*)d_in[24];
    const float* Wo = (const float*)d_in[25];
    const float* bo = (const float*)d_in[26];
    const float* fW1 = (const float*)d_in[27];
    const float* fb1 = (const float*)d_in[28];
    const float* fW2 = (const float*)d_in[29];
    const float* fb2 = (const float*)d_in[30];
    const float* rW1 = (const float*)d_in[31];
    const float* rb1 = (const float*)d_in[32];
    const float* rW2 = (const float*)d_in[33];
    const float* rb2 = (const float*)d_in[34];

    float* out0 = (float*)d_out;
    float* out1 = out0 + NN;
    float* out2 = out0 + 2*NN;

    float* ws = (float*)d_ws;
    size_t off = 0;
    unsigned char* xlf = (unsigned char*)(ws + off); off += (size_t)NN*32;  // NN*128 fp8
    _Float16* xrh = (_Float16*)(ws + off); off += (size_t)NN*64;            // NN*128 fp16
    float* xpA    = ws + off; off += (size_t)NN*32;
    float* xpB    = ws + off; off += (size_t)NN*32;
    int* counts   = (int*)(ws + off); off += NN;
    int* offs     = (int*)(ws + off); off += NN + 1;
    int* nxt      = (int*)(ws + off); off += NN + 1;
    int* bsum     = (int*)(ws + off); off += SBLK;
    off = (off + 1) & ~(size_t)1;            // 8B align for int2
    int2* esrc    = (int2*)(ws + off); off += (size_t)EE*2;
    off = (off + 3) & ~(size_t)3;            // 16B align for bf16x8 loads
    unsigned short* wfrag = (unsigned short*)(ws + off); off += 16*64*8/2;

    hipMemsetAsync(counts, 0, NN*sizeof(int), stream);
    prep_kernel<<<POOL_BLKS + WFRAG_BLKS + COUNT_BLKS, 256, 0, stream>>>(
        x, in_W, in_b, xpA, Wq, Wk, Wv, Wo, wfrag, ei, counts);
    bsum_kernel<<<SBLK, 256, 0, stream>>>(counts, bsum);
    scan2_kernel<<<SBLK, 256, 0, stream>>>(counts, bsum, offs, nxt);
    fill_kernel<<<(EE+255)/256, 256, 0, stream>>>(ei, ew, nxt, esrc);

    for (int layer = 0; layer < 2; layer++){
        const float* Wl   = (const float*)d_in[5 + 7*layer];
        const float* bl   = (const float*)d_in[6 + 7*layer];
        const float* Wr   = (const float*)d_in[7 + 7*layer];
        const float* br   = (const float*)d_in[8 + 7*layer];
        const float* We   = (const float*)d_in[9 + 7*layer];
        const float* att  = (const float*)d_in[10 + 7*layer];
        const float* bias = (const float*)d_in[11 + 7*layer];
        const float* xin  = layer ? xpB : xpA;
        float*       xout = layer ? xpA : xpB;
        linlr_kernel<<<NN/LNODES, 128, 0, stream>>>(xin, Wl, bl, Wr, br, xlf, xrh);
        gat_fused_kernel<<<NN, 256, 0, stream>>>(offs, esrc, xlf, xrh, We, att, bias, xout);
    }

    temporal_kernel<<<NN/4, 256, 0, stream>>>(x, xpA, in_W, in_b,
                                              bq, bk, bv, bo, wfrag,
                                              fW1, fb1, fW2, fb2, rW1, rb1, rW2, rb2,
                                              out0, out1, out2);
}